// Round 1
// baseline (1216.090 us; speedup 1.0000x reference)
//
#include <hip/hip_runtime.h>
#include <hip/hip_bf16.h>
#include <cstddef>

using bf16 = __hip_bfloat16;

#define B_   64
#define T_   512
#define V_   25
#define HD_  64
#define E_   48
#define NC_  60

__device__ __forceinline__ float b2f(bf16 x){ return __bfloat162float(x); }
__device__ __forceinline__ bf16  f2b(float x){ return __float2bfloat16(x); }

// ---------------- prep: CSR of edges grouped by dst ----------------
__global__ void k_csr(const int* __restrict__ ei, int* __restrict__ offs, int* __restrict__ lst)
{
  __shared__ int cnt[V_], pos[V_];
  int tid = threadIdx.x;
  if(tid < V_) cnt[tid] = 0;
  __syncthreads();
  if(tid == 0){
    for(int e=0;e<E_;e++) cnt[ei[2*e+1]]++;
    int off = 0;
    for(int v=0;v<V_;v++){ offs[v]=off; pos[v]=off; off+=cnt[v]; }
    offs[V_] = off;
    for(int e=0;e<E_;e++){ int d = ei[2*e+1]; lst[pos[d]++] = ei[2*e+0]; }
  }
}

// ---------------- prep: transpose conv weights to [k][in][out] ----------------
__global__ void k_wt(const float* __restrict__ c1W, const float* __restrict__ c2W,
                     float* __restrict__ c1Wt, float* __restrict__ c2Wt)
{
  const int n1 = 3*1600*64, n2 = 3*64*128;
  for(int i = blockIdx.x*blockDim.x + threadIdx.x; i < n1+n2; i += gridDim.x*blockDim.x){
    if(i < n1){
      int o = i & 63, vh = (i>>6) % 1600, k = i / 102400;
      c1Wt[i] = c1W[(o*1600+vh)*3 + k];
    } else {
      int j = i - n1;
      int o = j & 127, ci = (j>>7) & 63, k = j >> 13;
      c2Wt[j] = c2W[(o*64+ci)*3 + k];
    }
  }
}

// ---------------- GCN layer 1: X(B,C,T,V) -> Hpre (B,T,V,64) bf16, + stats ----------------
__global__ __launch_bounds__(256) void k_gcn1(
    const float* __restrict__ X, const float* __restrict__ s1W, const float* __restrict__ W1,
    const float* __restrict__ s1b, const int* __restrict__ offs, const int* __restrict__ lst,
    bf16* __restrict__ H, float* __restrict__ sum1, float* __restrict__ sq1)
{
  int t = blockIdx.x, b = blockIdx.y, tid = threadIdx.x;
  __shared__ float Xs[V_][4];
  __shared__ float ag[V_][4];
  __shared__ float sw[3][64], gw[3][64], bias[64];
  __shared__ int so[V_+1], sl[E_];
  __shared__ float ps[4][64], pq[4][64];
  if(tid < 192){ sw[tid/64][tid&63] = s1W[tid]; gw[tid/64][tid&63] = W1[tid]; }
  if(tid < 64) bias[tid] = s1b[tid];
  if(tid < V_+1) so[tid] = offs[tid];
  if(tid < E_) sl[tid] = lst[tid];
  if(tid < 75){ int c = tid/25, v = tid%25; Xs[v][c] = X[((size_t)(b*3+c)*T_ + t)*V_ + v]; }
  __syncthreads();
  if(tid < 75){
    int v = tid/3, c = tid%3;
    float s = 0.f;
    for(int e=so[v]; e<so[v+1]; e++) s += Xs[sl[e]][c];
    ag[v][c] = s;
  }
  __syncthreads();
  int h = tid & 63, vg = tid >> 6;
  float lsum = 0.f, lsq = 0.f;
  for(int v=vg; v<V_; v+=4){
    float acc = bias[h];
    for(int c=0;c<3;c++) acc += Xs[v][c]*sw[c][h] + ag[v][c]*gw[c][h];
    H[(((size_t)b*T_+t)*V_+v)*HD_ + h] = f2b(acc);
    lsum += acc; lsq += acc*acc;
  }
  ps[vg][h]=lsum; pq[vg][h]=lsq;
  __syncthreads();
  if(vg == 0){
    float s = ps[0][h]+ps[1][h]+ps[2][h]+ps[3][h];
    float q = pq[0][h]+pq[1][h]+pq[2][h]+pq[3][h];
    atomicAdd(&sum1[t*HD_+h], s);
    atomicAdd(&sq1[t*HD_+h], q);
  }
}

// ---------------- per-(t,h) BN finalize -> scale/shift ----------------
__global__ void k_bnfin_th(const float* __restrict__ sum, const float* __restrict__ sq,
                           const float* __restrict__ g, const float* __restrict__ bt,
                           float* __restrict__ scale, float* __restrict__ shift)
{
  int i = blockIdx.x*blockDim.x + threadIdx.x;
  if(i < T_*HD_){
    int h = i & 63;
    float m = sum[i] * (1.0f/1600.0f);
    float v = sq[i] * (1.0f/1600.0f) - m*m;
    float r = rsqrtf(fmaxf(v, 0.f) + 1e-5f);
    float sc = g[h]*r;
    scale[i] = sc;
    shift[i] = bt[h] - m*sc;
  }
}

// ---------------- GCN layer 2 (in-place on H buffer) ----------------
__global__ __launch_bounds__(256) void k_gcn2(
    const bf16* Hin, bf16* Hout,   // same pointer: no __restrict__ here
    const float* __restrict__ scale1, const float* __restrict__ shift1,
    const float* __restrict__ s2W, const float* __restrict__ W2, const float* __restrict__ s2b,
    const int* __restrict__ offs, const int* __restrict__ lst,
    float* __restrict__ sum2, float* __restrict__ sq2)
{
  int t = blockIdx.x, b = blockIdx.y, tid = threadIdx.x;
  __shared__ float Hn[V_][HD_];
  __shared__ float ag[V_][HD_];
  __shared__ float sw[HD_][HD_];
  __shared__ float gw[HD_][HD_];
  __shared__ float bias[64], scl[64], shf[64];
  __shared__ int so[V_+1], sl[E_];
  __shared__ float ps[4][64], pq[4][64];
  for(int i=tid; i<HD_*HD_; i+=256){ sw[i>>6][i&63] = s2W[i]; gw[i>>6][i&63] = W2[i]; }
  if(tid < 64){ bias[tid]=s2b[tid]; scl[tid]=scale1[t*64+tid]; shf[tid]=shift1[t*64+tid]; }
  if(tid < V_+1) so[tid]=offs[tid];
  if(tid < E_) sl[tid]=lst[tid];
  __syncthreads();
  size_t base = ((size_t)b*T_ + t) * V_ * HD_;
  for(int i=tid; i<V_*HD_; i+=256){
    int v = i>>6, c = i&63;
    float x = b2f(Hin[base+i])*scl[c] + shf[c];
    Hn[v][c] = fmaxf(x, 0.f);
  }
  __syncthreads();
  int h = tid & 63, vg = tid >> 6;
  for(int v=vg; v<V_; v+=4){
    float s = 0.f;
    for(int e=so[v]; e<so[v+1]; e++) s += Hn[sl[e]][h];
    ag[v][h] = s;
  }
  __syncthreads();
  float acc[7];
  #pragma unroll
  for(int j=0;j<7;j++) acc[j] = bias[h];
  for(int c4=0; c4<16; c4++){
    int c = c4*4;
    float w0=sw[c][h], w1=sw[c+1][h], w2=sw[c+2][h], w3=sw[c+3][h];
    float u0=gw[c][h], u1=gw[c+1][h], u2=gw[c+2][h], u3=gw[c+3][h];
    #pragma unroll
    for(int j=0;j<7;j++){
      int v = vg + 4*j;
      if(v < V_){
        float4 a  = *(const float4*)&Hn[v][c];
        float4 g4 = *(const float4*)&ag[v][c];
        acc[j] += a.x*w0 + a.y*w1 + a.z*w2 + a.w*w3
                + g4.x*u0 + g4.y*u1 + g4.z*u2 + g4.w*u3;
      }
    }
  }
  float lsum=0.f, lsq=0.f;
  #pragma unroll
  for(int j=0;j<7;j++){
    int v = vg + 4*j;
    if(v < V_){
      Hout[base + v*HD_ + h] = f2b(acc[j]);
      lsum += acc[j]; lsq += acc[j]*acc[j];
    }
  }
  ps[vg][h]=lsum; pq[vg][h]=lsq;
  __syncthreads();
  if(vg == 0){
    float s = ps[0][h]+ps[1][h]+ps[2][h]+ps[3][h];
    float q = pq[0][h]+pq[1][h]+pq[2][h]+pq[3][h];
    atomicAdd(&sum2[t*64+h], s);
    atomicAdd(&sq2[t*64+h], q);
  }
}

// ---------------- conv1: z(B,1600,T) = BN+ReLU(H), K=3 dil=1 pad=1 -> C1(B,64,T) ----------------
__global__ __launch_bounds__(256) void k_conv1(
    const bf16* __restrict__ H, const float* __restrict__ scale2, const float* __restrict__ shift2,
    const float* __restrict__ c1Wt, const float* __restrict__ c1b,
    float* __restrict__ C1, float* __restrict__ sum3, float* __restrict__ sq3)
{
  int b = blockIdx.y, t0 = blockIdx.x*64, tid = threadIdx.x;
  __shared__ float z[64][67];
  __shared__ float ps[64][17], pq[64][17];
  int og = tid & 15, tg = tid >> 4;
  int o0 = og*4;
  float acc[4][4];
  #pragma unroll
  for(int i=0;i<4;i++){
    #pragma unroll
    for(int j=0;j<4;j++) acc[i][j]=0.f;
  }
  for(int v=0; v<V_; v++){
    __syncthreads();
    for(int i=tid; i<66*64; i+=256){
      int hh = i & 63, ti = i >> 6;
      int t = t0 - 1 + ti;
      float val = 0.f;
      if(t >= 0 && t < T_){
        float x = b2f(H[(((size_t)b*T_+t)*V_+v)*HD_ + hh]);
        int si = t*64 + hh;
        val = fmaxf(x*scale2[si] + shift2[si], 0.f);
      }
      z[hh][ti] = val;
    }
    __syncthreads();
    for(int hh=0; hh<64; hh++){
      int vh = v*64 + hh;
      float4 w0 = *(const float4*)&c1Wt[0*102400 + vh*64 + o0];
      float4 w1 = *(const float4*)&c1Wt[1*102400 + vh*64 + o0];
      float4 w2 = *(const float4*)&c1Wt[2*102400 + vh*64 + o0];
      float zr[6];
      #pragma unroll
      for(int j=0;j<6;j++) zr[j] = z[hh][tg*4 + j];
      #pragma unroll
      for(int tt=0;tt<4;tt++){
        float z0=zr[tt], z1=zr[tt+1], z2=zr[tt+2];
        acc[tt][0] += w0.x*z0 + w1.x*z1 + w2.x*z2;
        acc[tt][1] += w0.y*z0 + w1.y*z1 + w2.y*z2;
        acc[tt][2] += w0.z*z0 + w1.z*z1 + w2.z*z2;
        acc[tt][3] += w0.w*z0 + w1.w*z1 + w2.w*z2;
      }
    }
  }
  #pragma unroll
  for(int oo=0;oo<4;oo++){
    float bsv = c1b[o0+oo];
    float s=0.f, q=0.f;
    #pragma unroll
    for(int tt=0;tt<4;tt++){
      float y = acc[tt][oo] + bsv;
      C1[((size_t)b*64 + o0+oo)*T_ + t0 + tg*4 + tt] = y;
      s += y; q += y*y;
    }
    ps[o0+oo][tg]=s; pq[o0+oo][tg]=q;
  }
  __syncthreads();
  if(tid < 64){
    float s=0.f, q=0.f;
    for(int g=0; g<16; g++){ s+=ps[tid][g]; q+=pq[tid][g]; }
    atomicAdd(&sum3[tid], s); atomicAdd(&sq3[tid], q);
  }
}

// ---------------- per-channel BN finalize ----------------
__global__ void k_bnfin_ch(const float* __restrict__ sum, const float* __restrict__ sq,
                           const float* __restrict__ g, const float* __restrict__ bt,
                           float* __restrict__ scale, float* __restrict__ shift,
                           int nch, float inv_count)
{
  int i = blockIdx.x*blockDim.x + threadIdx.x;
  if(i < nch){
    float m = sum[i]*inv_count;
    float v = sq[i]*inv_count - m*m;
    float r = rsqrtf(fmaxf(v, 0.f) + 1e-5f);
    float sc = g[i]*r;
    scale[i]=sc; shift[i]=bt[i]-m*sc;
  }
}

// ---------------- conv2: C1(B,64,T) BN+ReLU, K=3 dil=2 pad=2 -> C2(B,128,T) ----------------
__global__ __launch_bounds__(256) void k_conv2(
    const float* __restrict__ C1, const float* __restrict__ scale3, const float* __restrict__ shift3,
    const float* __restrict__ c2Wt, const float* __restrict__ c2b,
    float* __restrict__ C2, float* __restrict__ sum4, float* __restrict__ sq4)
{
  int b = blockIdx.y, t0 = blockIdx.x*64, tid = threadIdx.x;
  __shared__ float z[64][69];
  __shared__ float scl[64], shf[64];
  __shared__ float ps[128][9], pq[128][9];
  if(tid < 64){ scl[tid]=scale3[tid]; shf[tid]=shift3[tid]; }
  __syncthreads();
  for(int i=tid; i<64*68; i+=256){
    int ti = i % 68, ci = i / 68;
    int t = t0 - 2 + ti;
    float val = 0.f;
    if(t >= 0 && t < T_){
      val = fmaxf(C1[((size_t)b*64+ci)*T_ + t]*scl[ci] + shf[ci], 0.f);
    }
    z[ci][ti] = val;
  }
  __syncthreads();
  int og = tid & 31, tg = tid >> 5;
  int o0 = og*4;
  float acc[8][4];
  #pragma unroll
  for(int i=0;i<8;i++){
    #pragma unroll
    for(int j=0;j<4;j++) acc[i][j]=0.f;
  }
  for(int ci=0; ci<64; ci++){
    float4 w0 = *(const float4*)&c2Wt[0*8192 + ci*128 + o0];
    float4 w1 = *(const float4*)&c2Wt[1*8192 + ci*128 + o0];
    float4 w2 = *(const float4*)&c2Wt[2*8192 + ci*128 + o0];
    float zr[12];
    #pragma unroll
    for(int j=0;j<12;j++) zr[j] = z[ci][tg*8 + j];
    #pragma unroll
    for(int tt=0;tt<8;tt++){
      float z0=zr[tt], z1=zr[tt+2], z2=zr[tt+4];
      acc[tt][0] += w0.x*z0 + w1.x*z1 + w2.x*z2;
      acc[tt][1] += w0.y*z0 + w1.y*z1 + w2.y*z2;
      acc[tt][2] += w0.z*z0 + w1.z*z1 + w2.z*z2;
      acc[tt][3] += w0.w*z0 + w1.w*z1 + w2.w*z2;
    }
  }
  #pragma unroll
  for(int oo=0;oo<4;oo++){
    float bsv = c2b[o0+oo];
    float s=0.f, q=0.f;
    #pragma unroll
    for(int tt=0;tt<8;tt++){
      float y = acc[tt][oo] + bsv;
      C2[((size_t)b*128 + o0+oo)*T_ + t0 + tg*8 + tt] = y;
      s += y; q += y*y;
    }
    ps[o0+oo][tg]=s; pq[o0+oo][tg]=q;
  }
  __syncthreads();
  if(tid < 128){
    float s=0.f, q=0.f;
    for(int g=0; g<8; g++){ s+=ps[tid][g]; q+=pq[tid][g]; }
    atomicAdd(&sum4[tid], s); atomicAdd(&sq4[tid], q);
  }
}

// ---------------- head: BN+ReLU, mean over T, FC ----------------
__global__ __launch_bounds__(256) void k_head(
    const float* __restrict__ C2, const float* __restrict__ scale4, const float* __restrict__ shift4,
    const float* __restrict__ fcW, const float* __restrict__ fcb, float* __restrict__ out)
{
  int b = blockIdx.x, tid = threadIdx.x;
  __shared__ float mean[128];
  __shared__ float ms[256];
  int ch = tid >> 1, p = tid & 1;
  float scl = scale4[ch], shf = shift4[ch];
  const float* src = C2 + ((size_t)b*128 + ch)*T_ + p*256;
  float s = 0.f;
  for(int i=0;i<256;i++){
    s += fmaxf(src[i]*scl + shf, 0.f);
  }
  ms[tid] = s;
  __syncthreads();
  if(tid < 128) mean[tid] = (ms[2*tid] + ms[2*tid+1]) * (1.0f/512.0f);
  __syncthreads();
  if(tid < NC_){
    float acc = fcb[tid];
    for(int c=0;c<128;c++) acc += mean[c]*fcW[c*NC_ + tid];
    out[b*NC_ + tid] = acc;
  }
}

// ---------------- launch ----------------
extern "C" void kernel_launch(void* const* d_in, const int* in_sizes, int n_in,
                              void* d_out, int out_size, void* d_ws, size_t ws_size,
                              hipStream_t stream)
{
  const float* X   = (const float*)d_in[0];
  const int*   ei  = (const int*)  d_in[1];
  const float* W1  = (const float*)d_in[2];
  const float* s1W = (const float*)d_in[3];
  const float* s1b = (const float*)d_in[4];
  const float* g1  = (const float*)d_in[5];
  const float* b1  = (const float*)d_in[6];
  const float* W2  = (const float*)d_in[7];
  const float* s2W = (const float*)d_in[8];
  const float* s2b = (const float*)d_in[9];
  const float* g2  = (const float*)d_in[10];
  const float* b2  = (const float*)d_in[11];
  const float* c1W = (const float*)d_in[12];
  const float* c1b = (const float*)d_in[13];
  const float* tg1 = (const float*)d_in[14];
  const float* tb1 = (const float*)d_in[15];
  const float* c2W = (const float*)d_in[16];
  const float* c2b = (const float*)d_in[17];
  const float* tg2 = (const float*)d_in[18];
  const float* tb2 = (const float*)d_in[19];
  const float* fcW = (const float*)d_in[20];
  const float* fcb = (const float*)d_in[21];

  char* ws = (char*)d_ws;
  bf16*  H     = (bf16*) (ws);                       // 52,428,800 bf16 = 104,857,600 B
  float* C1    = (float*)(ws + 104857600);           // 2,097,152 f
  float* C2    = (float*)(ws + 113246208);           // 4,194,304 f
  float* c1Wt  = (float*)(ws + 130023424);           // 307,200 f
  float* c2Wt  = (float*)(ws + 131252224);           // 24,576 f
  float* stats = (float*)(ws + 131350528);
  float* sum1 = stats;            float* sq1 = stats + 32768;
  float* sum2 = stats + 65536;    float* sq2 = stats + 98304;
  float* sum3 = stats + 131072;   float* sq3 = sum3 + 64;
  float* sum4 = sq3 + 64;         float* sq4 = sum4 + 128;
  // zero region covers sum1..sq4 = 131072 + 384 floats
  float* scale1 = stats + 131456; float* shift1 = scale1 + 32768;
  float* scale2 = shift1 + 32768; float* shift2 = scale2 + 32768;
  float* scale3 = shift2 + 32768; float* shift3 = scale3 + 64;
  float* scale4 = shift3 + 64;    float* shift4 = scale4 + 128;
  int* csr_off = (int*)(shift4 + 128);
  int* csr_lst = csr_off + 32;

  hipMemsetAsync(stats, 0, (size_t)131456*sizeof(float), stream);
  k_csr<<<1, 64, 0, stream>>>(ei, csr_off, csr_lst);
  k_wt<<<256, 256, 0, stream>>>(c1W, c2W, c1Wt, c2Wt);

  k_gcn1<<<dim3(T_, B_), 256, 0, stream>>>(X, s1W, W1, s1b, csr_off, csr_lst, H, sum1, sq1);
  k_bnfin_th<<<128, 256, 0, stream>>>(sum1, sq1, g1, b1, scale1, shift1);
  k_gcn2<<<dim3(T_, B_), 256, 0, stream>>>(H, H, scale1, shift1, s2W, W2, s2b, csr_off, csr_lst, sum2, sq2);
  k_bnfin_th<<<128, 256, 0, stream>>>(sum2, sq2, g2, b2, scale2, shift2);
  k_conv1<<<dim3(8, B_), 256, 0, stream>>>(H, scale2, shift2, c1Wt, c1b, C1, sum3, sq3);
  k_bnfin_ch<<<1, 64, 0, stream>>>(sum3, sq3, tg1, tb1, scale3, shift3, 64, 1.0f/32768.0f);
  k_conv2<<<dim3(8, B_), 256, 0, stream>>>(C1, scale3, shift3, c2Wt, c2b, C2, sum4, sq4);
  k_bnfin_ch<<<1, 128, 0, stream>>>(sum4, sq4, tg2, tb2, scale4, shift4, 128, 1.0f/32768.0f);
  k_head<<<B_, 256, 0, stream>>>(C2, scale4, shift4, fcW, fcb, (float*)d_out);
}

// Round 2
// 772.721 us; speedup vs baseline: 1.5738x; 1.5738x over previous
//
#include <hip/hip_runtime.h>
#include <hip/hip_bf16.h>
#include <cstddef>

using bf16 = __hip_bfloat16;
typedef __attribute__((ext_vector_type(8)))  short bf16x8;
typedef __attribute__((ext_vector_type(16))) float f32x16;

#define B_   64
#define T_   512
#define V_   25
#define HD_  64
#define E_   48
#define NC_  60

__device__ __forceinline__ float b2f(bf16 x){ return __bfloat162float(x); }
__device__ __forceinline__ bf16  f2b(float x){ return __float2bfloat16(x); }
__device__ __forceinline__ unsigned short f2bits(float x){ return __builtin_bit_cast(unsigned short, f2b(x)); }
__device__ __forceinline__ float bits2f(unsigned short s){ return __builtin_bit_cast(float, ((unsigned)s)<<16); }

// ---------------- prep: CSR of edges grouped by dst ----------------
__global__ void k_csr(const int* __restrict__ ei, int* __restrict__ offs, int* __restrict__ lst)
{
  int tid = threadIdx.x;
  if(tid == 0){
    int cnt[V_], pos[V_];
    for(int v=0;v<V_;v++) cnt[v]=0;
    for(int e=0;e<E_;e++) cnt[ei[2*e+1]]++;
    int off = 0;
    for(int v=0;v<V_;v++){ offs[v]=off; pos[v]=off; off+=cnt[v]; }
    offs[V_] = off;
    for(int e=0;e<E_;e++){ int d = ei[2*e+1]; lst[pos[d]++] = ei[2*e+0]; }
  }
}

// ---------------- prep: conv1 weights -> bf16 MFMA-fragment layout; conv2 -> [k][in][out] ----------------
// Wb[((v*12 + kc)*64 + o)*16 + hlo] = bf16( c1W[(o*1600 + v*64 + (kc&3)*16 + hlo)*3 + (kc>>2)] )
__global__ void k_wt(const float* __restrict__ c1W, const float* __restrict__ c2W,
                     bf16* __restrict__ Wb, float* __restrict__ c2Wt)
{
  int i0 = blockIdx.x*blockDim.x + threadIdx.x, stride = gridDim.x*blockDim.x;
  for(int i = i0; i < 307200; i += stride){
    int hlo = i & 15, o = (i>>4)&63, kc = (i>>10)%12, v = i/12288;
    int ks = kc>>2, h = (kc&3)*16 + hlo;
    Wb[i] = f2b(c1W[(o*1600 + v*64 + h)*3 + ks]);
  }
  for(int i = i0; i < 24576; i += stride){
    int o = i & 127, ci = (i>>7)&63, k = i >> 13;
    c2Wt[i] = c2W[(o*64+ci)*3 + k];
  }
}

// ---------------- GCN layer 1: X(B,C,T,V) -> Hpre (B,T,V,64) bf16, + stats ----------------
__global__ __launch_bounds__(256) void k_gcn1(
    const float* __restrict__ X, const float* __restrict__ s1W, const float* __restrict__ W1,
    const float* __restrict__ s1b, const int* __restrict__ offs, const int* __restrict__ lst,
    bf16* __restrict__ H, float* __restrict__ sum1, float* __restrict__ sq1)
{
  int t = blockIdx.x, b = blockIdx.y, tid = threadIdx.x;
  __shared__ float Xs[V_][4];
  __shared__ float ag[V_][4];
  __shared__ float sw[3][64], gw[3][64], bias[64];
  __shared__ int so[V_+1], sl[E_];
  __shared__ float ps[4][64], pq[4][64];
  if(tid < 192){ sw[tid/64][tid&63] = s1W[tid]; gw[tid/64][tid&63] = W1[tid]; }
  if(tid < 64) bias[tid] = s1b[tid];
  if(tid < V_+1) so[tid] = offs[tid];
  if(tid < E_) sl[tid] = lst[tid];
  if(tid < 75){ int c = tid/25, v = tid%25; Xs[v][c] = X[((size_t)(b*3+c)*T_ + t)*V_ + v]; }
  __syncthreads();
  if(tid < 75){
    int v = tid/3, c = tid%3;
    float s = 0.f;
    for(int e=so[v]; e<so[v+1]; e++) s += Xs[sl[e]][c];
    ag[v][c] = s;
  }
  __syncthreads();
  int h = tid & 63, vg = tid >> 6;
  float lsum = 0.f, lsq = 0.f;
  for(int v=vg; v<V_; v+=4){
    float acc = bias[h];
    for(int c=0;c<3;c++) acc += Xs[v][c]*sw[c][h] + ag[v][c]*gw[c][h];
    H[(((size_t)b*T_+t)*V_+v)*HD_ + h] = f2b(acc);
    lsum += acc; lsq += acc*acc;
  }
  ps[vg][h]=lsum; pq[vg][h]=lsq;
  __syncthreads();
  if(vg == 0){
    float s = ps[0][h]+ps[1][h]+ps[2][h]+ps[3][h];
    float q = pq[0][h]+pq[1][h]+pq[2][h]+pq[3][h];
    atomicAdd(&sum1[t*HD_+h], s);
    atomicAdd(&sq1[t*HD_+h], q);
  }
}

// ---------------- per-(t,h) BN finalize -> scale/shift ----------------
__global__ void k_bnfin_th(const float* __restrict__ sum, const float* __restrict__ sq,
                           const float* __restrict__ g, const float* __restrict__ bt,
                           float* __restrict__ scale, float* __restrict__ shift)
{
  int i = blockIdx.x*blockDim.x + threadIdx.x;
  if(i < T_*HD_){
    int h = i & 63;
    float m = sum[i] * (1.0f/1600.0f);
    float v = sq[i] * (1.0f/1600.0f) - m*m;
    float r = rsqrtf(fmaxf(v, 0.f) + 1e-5f);
    float sc = g[h]*r;
    scale[i] = sc;
    shift[i] = bt[h] - m*sc;
  }
}

// ---------------- GCN layer 2 (in-place on H buffer) ----------------
__global__ __launch_bounds__(256) void k_gcn2(
    const bf16* Hin, bf16* Hout,   // same pointer: no __restrict__ here
    const float* __restrict__ scale1, const float* __restrict__ shift1,
    const float* __restrict__ s2W, const float* __restrict__ W2, const float* __restrict__ s2b,
    const int* __restrict__ offs, const int* __restrict__ lst,
    float* __restrict__ sum2, float* __restrict__ sq2)
{
  int t = blockIdx.x, b = blockIdx.y, tid = threadIdx.x;
  __shared__ float Hn[V_][HD_];
  __shared__ float ag[V_][HD_];
  __shared__ float sw[HD_][HD_];
  __shared__ float gw[HD_][HD_];
  __shared__ float bias[64], scl[64], shf[64];
  __shared__ int so[V_+1], sl[E_];
  __shared__ float ps[4][64], pq[4][64];
  for(int i=tid; i<HD_*HD_; i+=256){ sw[i>>6][i&63] = s2W[i]; gw[i>>6][i&63] = W2[i]; }
  if(tid < 64){ bias[tid]=s2b[tid]; scl[tid]=scale1[t*64+tid]; shf[tid]=shift1[t*64+tid]; }
  if(tid < V_+1) so[tid]=offs[tid];
  if(tid < E_) sl[tid]=lst[tid];
  __syncthreads();
  size_t base = ((size_t)b*T_ + t) * V_ * HD_;
  for(int i=tid; i<V_*HD_; i+=256){
    int v = i>>6, c = i&63;
    float x = b2f(Hin[base+i])*scl[c] + shf[c];
    Hn[v][c] = fmaxf(x, 0.f);
  }
  __syncthreads();
  int h = tid & 63, vg = tid >> 6;
  for(int v=vg; v<V_; v+=4){
    float s = 0.f;
    for(int e=so[v]; e<so[v+1]; e++) s += Hn[sl[e]][h];
    ag[v][h] = s;
  }
  __syncthreads();
  float acc[7];
  #pragma unroll
  for(int j=0;j<7;j++) acc[j] = bias[h];
  for(int c4=0; c4<16; c4++){
    int c = c4*4;
    float w0=sw[c][h], w1=sw[c+1][h], w2=sw[c+2][h], w3=sw[c+3][h];
    float u0=gw[c][h], u1=gw[c+1][h], u2=gw[c+2][h], u3=gw[c+3][h];
    #pragma unroll
    for(int j=0;j<7;j++){
      int v = vg + 4*j;
      if(v < V_){
        float4 a  = *(const float4*)&Hn[v][c];
        float4 g4 = *(const float4*)&ag[v][c];
        acc[j] += a.x*w0 + a.y*w1 + a.z*w2 + a.w*w3
                + g4.x*u0 + g4.y*u1 + g4.z*u2 + g4.w*u3;
      }
    }
  }
  float lsum=0.f, lsq=0.f;
  #pragma unroll
  for(int j=0;j<7;j++){
    int v = vg + 4*j;
    if(v < V_){
      Hout[base + v*HD_ + h] = f2b(acc[j]);
      lsum += acc[j]; lsq += acc[j]*acc[j];
    }
  }
  ps[vg][h]=lsum; pq[vg][h]=lsq;
  __syncthreads();
  if(vg == 0){
    float s = ps[0][h]+ps[1][h]+ps[2][h]+ps[3][h];
    float q = pq[0][h]+pq[1][h]+pq[2][h]+pq[3][h];
    atomicAdd(&sum2[t*64+h], s);
    atomicAdd(&sq2[t*64+h], q);
  }
}

// ---------------- conv1 via MFMA 32x32x16 bf16 ----------------
// out[o][t] = sum_{v,h,ks} W[o][v*64+h][ks] * z[v,h][t+ks-1],  z = relu(bn2(H))
// block: 64 o x 64 t (one b, one t-tile). 4 waves, each 32o x 32t -> one 32x32 C frag.
__device__ __forceinline__ bf16x8 loadH8(const bf16* H, int b, int v, int t0, int s){
  int ti = s>>3, h0 = (s&7)*8, t = t0-1+ti;
  bf16x8 r = {0,0,0,0,0,0,0,0};
  if(t >= 0 && t < T_) r = *(const bf16x8*)&H[(((size_t)b*T_+t)*V_ + v)*HD_ + h0];
  return r;
}

__device__ __forceinline__ void xform_store(short* zbuf, const unsigned int* sshf, int s, bf16x8 raw){
  int ti = s>>3, h0 = (s&7)*8;
  uint4 u0 = *(const uint4*)&sshf[ti*64 + h0];
  uint4 u1 = *(const uint4*)&sshf[ti*64 + h0 + 4];
  unsigned int uu[8] = {u0.x,u0.y,u0.z,u0.w,u1.x,u1.y,u1.z,u1.w};
  bf16x8 outv;
  #pragma unroll
  for(int j=0;j<8;j++){
    float scl = bits2f((unsigned short)(uu[j] & 0xffffu));
    float shf = bits2f((unsigned short)(uu[j] >> 16));
    float x = bits2f((unsigned short)raw[j]);
    outv[j] = (short)f2bits(fmaxf(x*scl + shf, 0.f));
  }
  *(bf16x8*)&zbuf[ti*72 + h0] = outv;
}

__global__ __launch_bounds__(256,2) void k_conv1(
    const bf16* __restrict__ H, const float* __restrict__ scale2, const float* __restrict__ shift2,
    const bf16* __restrict__ Wb, const float* __restrict__ c1b, float* __restrict__ C1)
{
  int b = blockIdx.y, t0 = blockIdx.x*64, tid = threadIdx.x;
  int lane = tid & 63, w = tid >> 6;
  __shared__ unsigned int sshf[66*64];     // packed {shift,scale} bf16 pairs
  __shared__ short zs[2][66*72];           // z tile, rows padded to 72 bf16

  for(int i = tid; i < 66*64; i += 256){
    int ti = i>>6, h = i&63, t = t0-1+ti;
    unsigned int u = 0;
    if(t >= 0 && t < T_){
      u = ((unsigned)f2bits(shift2[t*64+h])<<16) | f2bits(scale2[t*64+h]);
    }
    sshf[i] = u;
  }
  __syncthreads();

  { // stage v=0
    bf16x8 a0 = loadH8(H,b,0,t0,tid);
    bf16x8 a1 = loadH8(H,b,0,t0,tid+256);
    bf16x8 a2 = {0,0,0,0,0,0,0,0};
    if(tid<16) a2 = loadH8(H,b,0,t0,tid+512);
    xform_store(zs[0], sshf, tid, a0);
    xform_store(zs[0], sshf, tid+256, a1);
    if(tid<16) xform_store(zs[0], sshf, tid+512, a2);
  }
  __syncthreads();

  int ow = w & 1, twv = (w>>1)*32;
  int o0 = ow*32;
  f32x16 acc = {};
  for(int v=0; v<25; v++){
    int cur = v & 1;
    bf16x8 a0={0,0,0,0,0,0,0,0}, a1={0,0,0,0,0,0,0,0}, a2={0,0,0,0,0,0,0,0};
    if(v < 24){
      a0 = loadH8(H,b,v+1,t0,tid);
      a1 = loadH8(H,b,v+1,t0,tid+256);
      if(tid<16) a2 = loadH8(H,b,v+1,t0,tid+512);
    }
    const short* zbuf = zs[cur];
    #pragma unroll
    for(int kc=0; kc<12; kc++){
      int ks = kc>>2;
      bf16x8 af = *(const bf16x8*)&Wb[((v*12+kc)*64 + o0 + (lane&31))*16 + (lane>>5)*8];
      int row = twv + (lane&31) + ks;
      int col = (kc&3)*16 + (lane>>5)*8;
      bf16x8 bfr = *(const bf16x8*)&zbuf[row*72 + col];
      acc = __builtin_amdgcn_mfma_f32_32x32x16_bf16(af, bfr, acc, 0, 0, 0);
    }
    if(v < 24){
      short* znext = zs[cur^1];
      xform_store(znext, sshf, tid, a0);
      xform_store(znext, sshf, tid+256, a1);
      if(tid<16) xform_store(znext, sshf, tid+512, a2);
    }
    __syncthreads();
  }
  int t = t0 + twv + (lane&31);
  #pragma unroll
  for(int r=0;r<16;r++){
    int o = o0 + (r&3) + 8*(r>>2) + 4*(lane>>5);
    C1[((size_t)b*64 + o)*T_ + t] = acc[r] + c1b[o];
  }
}

// ---------------- BN3 stats from C1 (no atomics) ----------------
__global__ __launch_bounds__(256) void k_stats3(const float* __restrict__ C1,
                                                float* __restrict__ sum3, float* __restrict__ sq3)
{
  int o = blockIdx.x, tid = threadIdx.x;
  float s=0.f, q=0.f;
  for(int idx = tid; idx < 64*128; idx += 256){
    int b = idx >> 7, t4 = idx & 127;
    float4 vv = *(const float4*)&C1[((size_t)(b*64+o))*T_ + t4*4];
    s += vv.x+vv.y+vv.z+vv.w;
    q += vv.x*vv.x + vv.y*vv.y + vv.z*vv.z + vv.w*vv.w;
  }
  __shared__ float rs[4], rq[4];
  for(int off=32; off; off>>=1){ s += __shfl_down(s, off); q += __shfl_down(q, off); }
  if((tid&63)==0){ rs[tid>>6]=s; rq[tid>>6]=q; }
  __syncthreads();
  if(tid==0){ sum3[o] = rs[0]+rs[1]+rs[2]+rs[3]; sq3[o] = rq[0]+rq[1]+rq[2]+rq[3]; }
}

// ---------------- per-channel BN finalize ----------------
__global__ void k_bnfin_ch(const float* __restrict__ sum, const float* __restrict__ sq,
                           const float* __restrict__ g, const float* __restrict__ bt,
                           float* __restrict__ scale, float* __restrict__ shift,
                           int nch, float inv_count)
{
  int i = blockIdx.x*blockDim.x + threadIdx.x;
  if(i < nch){
    float m = sum[i]*inv_count;
    float v = sq[i]*inv_count - m*m;
    float r = rsqrtf(fmaxf(v, 0.f) + 1e-5f);
    float sc = g[i]*r;
    scale[i]=sc; shift[i]=bt[i]-m*sc;
  }
}

// ---------------- conv2: C1(B,64,T) BN+ReLU, K=3 dil=2 pad=2 -> C2(B,128,T) ----------------
__global__ __launch_bounds__(256) void k_conv2(
    const float* __restrict__ C1, const float* __restrict__ scale3, const float* __restrict__ shift3,
    const float* __restrict__ c2Wt, const float* __restrict__ c2b,
    float* __restrict__ C2, float* __restrict__ sum4, float* __restrict__ sq4)
{
  int b = blockIdx.y, t0 = blockIdx.x*64, tid = threadIdx.x;
  __shared__ float z[64][69];
  __shared__ float scl[64], shf[64];
  __shared__ float ps[128][9], pq[128][9];
  if(tid < 64){ scl[tid]=scale3[tid]; shf[tid]=shift3[tid]; }
  __syncthreads();
  for(int i=tid; i<64*68; i+=256){
    int ti = i % 68, ci = i / 68;
    int t = t0 - 2 + ti;
    float val = 0.f;
    if(t >= 0 && t < T_){
      val = fmaxf(C1[((size_t)b*64+ci)*T_ + t]*scl[ci] + shf[ci], 0.f);
    }
    z[ci][ti] = val;
  }
  __syncthreads();
  int og = tid & 31, tg = tid >> 5;
  int o0 = og*4;
  float acc[8][4];
  #pragma unroll
  for(int i=0;i<8;i++){
    #pragma unroll
    for(int j=0;j<4;j++) acc[i][j]=0.f;
  }
  for(int ci=0; ci<64; ci++){
    float4 w0 = *(const float4*)&c2Wt[0*8192 + ci*128 + o0];
    float4 w1 = *(const float4*)&c2Wt[1*8192 + ci*128 + o0];
    float4 w2 = *(const float4*)&c2Wt[2*8192 + ci*128 + o0];
    float zr[12];
    #pragma unroll
    for(int j=0;j<12;j++) zr[j] = z[ci][tg*8 + j];
    #pragma unroll
    for(int tt=0;tt<8;tt++){
      float z0=zr[tt], z1=zr[tt+2], z2=zr[tt+4];
      acc[tt][0] += w0.x*z0 + w1.x*z1 + w2.x*z2;
      acc[tt][1] += w0.y*z0 + w1.y*z1 + w2.y*z2;
      acc[tt][2] += w0.z*z0 + w1.z*z1 + w2.z*z2;
      acc[tt][3] += w0.w*z0 + w1.w*z1 + w2.w*z2;
    }
  }
  #pragma unroll
  for(int oo=0;oo<4;oo++){
    float bsv = c2b[o0+oo];
    float s=0.f, q=0.f;
    #pragma unroll
    for(int tt=0;tt<8;tt++){
      float y = acc[tt][oo] + bsv;
      C2[((size_t)b*128 + o0+oo)*T_ + t0 + tg*8 + tt] = y;
      s += y; q += y*y;
    }
    ps[o0+oo][tg]=s; pq[o0+oo][tg]=q;
  }
  __syncthreads();
  if(tid < 128){
    float s=0.f, q=0.f;
    for(int g=0; g<8; g++){ s+=ps[tid][g]; q+=pq[tid][g]; }
    atomicAdd(&sum4[tid], s); atomicAdd(&sq4[tid], q);
  }
}

// ---------------- head: BN+ReLU, mean over T, FC ----------------
__global__ __launch_bounds__(256) void k_head(
    const float* __restrict__ C2, const float* __restrict__ scale4, const float* __restrict__ shift4,
    const float* __restrict__ fcW, const float* __restrict__ fcb, float* __restrict__ out)
{
  int b = blockIdx.x, tid = threadIdx.x;
  __shared__ float mean[128];
  __shared__ float ms[256];
  int ch = tid >> 1, p = tid & 1;
  float scl = scale4[ch], shf = shift4[ch];
  const float* src = C2 + ((size_t)b*128 + ch)*T_ + p*256;
  float s = 0.f;
  for(int i=0;i<256;i++){
    s += fmaxf(src[i]*scl + shf, 0.f);
  }
  ms[tid] = s;
  __syncthreads();
  if(tid < 128) mean[tid] = (ms[2*tid] + ms[2*tid+1]) * (1.0f/512.0f);
  __syncthreads();
  if(tid < NC_){
    float acc = fcb[tid];
    for(int c=0;c<128;c++) acc += mean[c]*fcW[c*NC_ + tid];
    out[b*NC_ + tid] = acc;
  }
}

// ---------------- launch ----------------
extern "C" void kernel_launch(void* const* d_in, const int* in_sizes, int n_in,
                              void* d_out, int out_size, void* d_ws, size_t ws_size,
                              hipStream_t stream)
{
  const float* X   = (const float*)d_in[0];
  const int*   ei  = (const int*)  d_in[1];
  const float* W1  = (const float*)d_in[2];
  const float* s1W = (const float*)d_in[3];
  const float* s1b = (const float*)d_in[4];
  const float* g1  = (const float*)d_in[5];
  const float* b1  = (const float*)d_in[6];
  const float* W2  = (const float*)d_in[7];
  const float* s2W = (const float*)d_in[8];
  const float* s2b = (const float*)d_in[9];
  const float* g2  = (const float*)d_in[10];
  const float* b2  = (const float*)d_in[11];
  const float* c1W = (const float*)d_in[12];
  const float* c1b = (const float*)d_in[13];
  const float* tg1 = (const float*)d_in[14];
  const float* tb1 = (const float*)d_in[15];
  const float* c2W = (const float*)d_in[16];
  const float* c2b = (const float*)d_in[17];
  const float* tg2 = (const float*)d_in[18];
  const float* tb2 = (const float*)d_in[19];
  const float* fcW = (const float*)d_in[20];
  const float* fcb = (const float*)d_in[21];

  char* ws = (char*)d_ws;
  bf16*  H     = (bf16*) (ws);                       // 52,428,800 bf16 = 104,857,600 B
  float* C1    = (float*)(ws + 104857600);           // 2,097,152 f
  float* C2    = (float*)(ws + 113246208);           // 4,194,304 f
  bf16*  Wb    = (bf16*) (ws + 130023424);           // 307,200 bf16 (conv1 fragment layout)
  float* c2Wt  = (float*)(ws + 131252224);           // 24,576 f
  float* stats = (float*)(ws + 131350528);
  float* sum1 = stats;            float* sq1 = stats + 32768;
  float* sum2 = stats + 65536;    float* sq2 = stats + 98304;
  float* sum3 = stats + 131072;   float* sq3 = sum3 + 64;
  float* sum4 = sq3 + 64;         float* sq4 = sum4 + 128;
  float* scale1 = stats + 131456; float* shift1 = scale1 + 32768;
  float* scale2 = shift1 + 32768; float* shift2 = scale2 + 32768;
  float* scale3 = shift2 + 32768; float* shift3 = scale3 + 64;
  float* scale4 = shift3 + 64;    float* shift4 = scale4 + 128;
  int* csr_off = (int*)(shift4 + 128);
  int* csr_lst = csr_off + 32;

  hipMemsetAsync(stats, 0, (size_t)131456*sizeof(float), stream);
  k_csr<<<1, 64, 0, stream>>>(ei, csr_off, csr_lst);
  k_wt<<<256, 256, 0, stream>>>(c1W, c2W, Wb, c2Wt);

  k_gcn1<<<dim3(T_, B_), 256, 0, stream>>>(X, s1W, W1, s1b, csr_off, csr_lst, H, sum1, sq1);
  k_bnfin_th<<<128, 256, 0, stream>>>(sum1, sq1, g1, b1, scale1, shift1);
  k_gcn2<<<dim3(T_, B_), 256, 0, stream>>>(H, H, scale1, shift1, s2W, W2, s2b, csr_off, csr_lst, sum2, sq2);
  k_bnfin_th<<<128, 256, 0, stream>>>(sum2, sq2, g2, b2, scale2, shift2);
  k_conv1<<<dim3(8, B_), 256, 0, stream>>>(H, scale2, shift2, Wb, c1b, C1);
  k_stats3<<<64, 256, 0, stream>>>(C1, sum3, sq3);
  k_bnfin_ch<<<1, 64, 0, stream>>>(sum3, sq3, tg1, tb1, scale3, shift3, 64, 1.0f/32768.0f);
  k_conv2<<<dim3(8, B_), 256, 0, stream>>>(C1, scale3, shift3, c2Wt, c2b, C2, sum4, sq4);
  k_bnfin_ch<<<1, 128, 0, stream>>>(sum4, sq4, tg2, tb2, scale4, shift4, 128, 1.0f/32768.0f);
  k_head<<<B_, 256, 0, stream>>>(C2, scale4, shift4, fcW, fcb, (float*)d_out);
}

// Round 3
// 335.384 us; speedup vs baseline: 3.6260x; 2.3040x over previous
//
#include <hip/hip_runtime.h>
#include <hip/hip_bf16.h>
#include <cstddef>

using bf16 = __hip_bfloat16;
typedef __attribute__((ext_vector_type(8)))  short bf16x8;
typedef __attribute__((ext_vector_type(4)))  float f32x4;
typedef __attribute__((ext_vector_type(16))) float f32x16;

#define B_   64
#define T_   512
#define V_   25
#define HD_  64
#define E_   48
#define NC_  60

__device__ __forceinline__ float b2f(bf16 x){ return __bfloat162float(x); }
__device__ __forceinline__ bf16  f2b(float x){ return __float2bfloat16(x); }
__device__ __forceinline__ unsigned short f2bits(float x){ return __builtin_bit_cast(unsigned short, f2b(x)); }
__device__ __forceinline__ float bits2f(unsigned short s){ return __builtin_bit_cast(float, ((unsigned)s)<<16); }

// ---------------- prep: CSR of edges grouped by dst ----------------
__global__ void k_csr(const int* __restrict__ ei, int* __restrict__ offs, int* __restrict__ lst)
{
  int tid = threadIdx.x;
  if(tid == 0){
    int cnt[V_], pos[V_];
    for(int v=0;v<V_;v++) cnt[v]=0;
    for(int e=0;e<E_;e++) cnt[ei[2*e+1]]++;
    int off = 0;
    for(int v=0;v<V_;v++){ offs[v]=off; pos[v]=off; off+=cnt[v]; }
    offs[V_] = off;
    for(int e=0;e<E_;e++){ int d = ei[2*e+1]; lst[pos[d]++] = ei[2*e+0]; }
  }
}

// ---------------- prep: weight packing ----------------
// Wb  : conv1 weights -> 32x32x16 A-frag layout
// WbB : gcn2 cat-weights [s2W;W2] (128x64) -> 16x16x32 B-frag layout
//       WbB[((kt*4+n)*64+l)*8+j] = Wcat[kt*32 + (l>>4)*8 + j][n*16 + (l&15)]
__global__ void k_wt(const float* __restrict__ c1W, const float* __restrict__ c2W,
                     const float* __restrict__ s2W, const float* __restrict__ W2,
                     bf16* __restrict__ Wb, float* __restrict__ c2Wt, bf16* __restrict__ WbB)
{
  int i0 = blockIdx.x*blockDim.x + threadIdx.x, stride = gridDim.x*blockDim.x;
  for(int i = i0; i < 307200; i += stride){
    int hlo = i & 15, o = (i>>4)&63, kc = (i>>10)%12, v = i/12288;
    int ks = kc>>2, h = (kc&3)*16 + hlo;
    Wb[i] = f2b(c1W[(o*1600 + v*64 + h)*3 + ks]);
  }
  for(int i = i0; i < 24576; i += stride){
    int o = i & 127, ci = (i>>7)&63, k = i >> 13;
    c2Wt[i] = c2W[(o*64+ci)*3 + k];
  }
  for(int i = i0; i < 8192; i += stride){
    int j = i&7, l=(i>>3)&63, n=(i>>9)&3, kt=i>>11;
    int k = kt*32 + (l>>4)*8 + j;
    int h = n*16 + (l&15);
    float val = (k < 64) ? s2W[k*64 + h] : W2[(k-64)*64 + h];
    WbB[i] = f2b(val);
  }
}

// ---------------- GCN layer 1: X(B,C,T,V) -> Hpre (B,T,V,64) bf16, + stats ----------------
__global__ __launch_bounds__(256) void k_gcn1(
    const float* __restrict__ X, const float* __restrict__ s1W, const float* __restrict__ W1,
    const float* __restrict__ s1b, const int* __restrict__ offs, const int* __restrict__ lst,
    bf16* __restrict__ H, float* __restrict__ sum1, float* __restrict__ sq1)
{
  int t = blockIdx.x, b = blockIdx.y, tid = threadIdx.x;
  __shared__ float Xs[V_][4];
  __shared__ float ag[V_][4];
  __shared__ float sw[3][64], gw[3][64], bias[64];
  __shared__ int so[V_+1], sl[E_];
  __shared__ float ps[4][64], pq[4][64];
  if(tid < 192){ sw[tid/64][tid&63] = s1W[tid]; gw[tid/64][tid&63] = W1[tid]; }
  if(tid < 64) bias[tid] = s1b[tid];
  if(tid < V_+1) so[tid] = offs[tid];
  if(tid < E_) sl[tid] = lst[tid];
  if(tid < 75){ int c = tid/25, v = tid%25; Xs[v][c] = X[((size_t)(b*3+c)*T_ + t)*V_ + v]; }
  __syncthreads();
  if(tid < 75){
    int v = tid/3, c = tid%3;
    float s = 0.f;
    for(int e=so[v]; e<so[v+1]; e++) s += Xs[sl[e]][c];
    ag[v][c] = s;
  }
  __syncthreads();
  int h = tid & 63, vg = tid >> 6;
  float lsum = 0.f, lsq = 0.f;
  for(int v=vg; v<V_; v+=4){
    float acc = bias[h];
    for(int c=0;c<3;c++) acc += Xs[v][c]*sw[c][h] + ag[v][c]*gw[c][h];
    H[(((size_t)b*T_+t)*V_+v)*HD_ + h] = f2b(acc);
    lsum += acc; lsq += acc*acc;
  }
  ps[vg][h]=lsum; pq[vg][h]=lsq;
  __syncthreads();
  if(vg == 0){
    float s = ps[0][h]+ps[1][h]+ps[2][h]+ps[3][h];
    float q = pq[0][h]+pq[1][h]+pq[2][h]+pq[3][h];
    atomicAdd(&sum1[t*HD_+h], s);
    atomicAdd(&sq1[t*HD_+h], q);
  }
}

// ---------------- per-(t,h) BN finalize -> scale/shift ----------------
__global__ void k_bnfin_th(const float* __restrict__ sum, const float* __restrict__ sq,
                           const float* __restrict__ g, const float* __restrict__ bt,
                           float* __restrict__ scale, float* __restrict__ shift)
{
  int i = blockIdx.x*blockDim.x + threadIdx.x;
  if(i < T_*HD_){
    int h = i & 63;
    float m = sum[i] * (1.0f/1600.0f);
    float v = sq[i] * (1.0f/1600.0f) - m*m;
    float r = rsqrtf(fmaxf(v, 0.f) + 1e-5f);
    float sc = g[h]*r;
    scale[i] = sc;
    shift[i] = bt[h] - m*sc;
  }
}

// ---------------- GCN layer 2 via MFMA 16x16x32 (in-place on H) ----------------
// Rows r = v*16 + t_local (400 rows per block), K = 128 = [Hn | Adj@Hn], N = 64.
__global__ __launch_bounds__(512,2) void k_gcn2(
    const bf16* Hin, bf16* Hout,   // same pointer
    const float* __restrict__ scale1, const float* __restrict__ shift1,
    const bf16* __restrict__ WbB, const float* __restrict__ s2b,
    const int* __restrict__ offs, const int* __restrict__ lst,
    float* __restrict__ sum2, float* __restrict__ sq2)
{
  int tid = threadIdx.x, lane = tid & 63, wid = tid >> 6;
  int b = blockIdx.y, t0 = blockIdx.x*16;
  __shared__ short Z[400*136];      // 108,800 B ; rows padded to 136 bf16 (272 B)
  __shared__ float scl[1024], shf[1024];
  __shared__ int so[V_+1], sl[E_];

  // weight B-frags, held in registers for the whole block
  bf16x8 wfrag[16];
  #pragma unroll
  for(int i=0;i<16;i++) wfrag[i] = *(const bf16x8*)&WbB[(i*64 + lane)*8];
  float bias[4];
  #pragma unroll
  for(int n=0;n<4;n++) bias[n] = s2b[n*16 + (lane&15)];

  if(tid < V_+1) so[tid]=offs[tid];
  if(tid >= 64 && tid < 64+E_) sl[tid-64]=lst[tid-64];
  for(int i=tid; i<1024; i+=512){
    scl[i] = scale1[t0*64 + i];
    shf[i] = shift1[t0*64 + i];
  }
  __syncthreads();

  // ---- stage Hn = relu(bn1(H)) into Z[:, 0:64] ----
  const bf16* hbase = Hin + ((size_t)b*T_ + t0)*V_*64;
  for(int c=tid; c<3200; c+=512){
    int h8 = c & 7, rr = c >> 3;          // rr = t_local*25 + v (global-contiguous)
    int tl = rr/25, v = rr - tl*25;
    bf16x8 raw = *(const bf16x8*)&hbase[(size_t)rr*64 + h8*8];
    float4 s0 = *(const float4*)&scl[tl*64 + h8*8];
    float4 s1 = *(const float4*)&scl[tl*64 + h8*8 + 4];
    float4 f0 = *(const float4*)&shf[tl*64 + h8*8];
    float4 f1 = *(const float4*)&shf[tl*64 + h8*8 + 4];
    float sv[8] = {s0.x,s0.y,s0.z,s0.w,s1.x,s1.y,s1.z,s1.w};
    float fv[8] = {f0.x,f0.y,f0.z,f0.w,f1.x,f1.y,f1.z,f1.w};
    bf16x8 o;
    #pragma unroll
    for(int j=0;j<8;j++){
      float x = bits2f((unsigned short)raw[j])*sv[j] + fv[j];
      o[j] = (short)f2bits(fmaxf(x, 0.f));
    }
    *(bf16x8*)&Z[(v*16 + tl)*136 + h8*8] = o;
  }
  __syncthreads();

  // ---- aggregate neighbors into Z[:, 64:128] ----
  for(int c=tid; c<3200; c+=512){
    int h8 = c & 7, r = c >> 3;           // r = v*16 + t_local
    int v = r >> 4, tl = r & 15;
    float accv[8];
    #pragma unroll
    for(int j=0;j<8;j++) accv[j] = 0.f;
    for(int e=so[v]; e<so[v+1]; e++){
      int u = sl[e];
      bf16x8 nb = *(const bf16x8*)&Z[(u*16 + tl)*136 + h8*8];
      #pragma unroll
      for(int j=0;j<8;j++) accv[j] += bits2f((unsigned short)nb[j]);
    }
    bf16x8 o;
    #pragma unroll
    for(int j=0;j<8;j++) o[j] = (short)f2bits(accv[j]);
    *(bf16x8*)&Z[r*136 + 64 + h8*8] = o;
  }
  __syncthreads();

  // ---- MFMA: each wave takes v-tiles round-robin ----
  f32x4 ssum[4] = {}, ssq[4] = {};
  for(int v=wid; v<V_; v+=8){
    f32x4 acc[4] = {};
    bf16x8 afr[4];
    #pragma unroll
    for(int kt=0;kt<4;kt++)
      afr[kt] = *(const bf16x8*)&Z[(v*16 + (lane&15))*136 + kt*32 + (lane>>4)*8];
    #pragma unroll
    for(int kt=0;kt<4;kt++){
      #pragma unroll
      for(int n=0;n<4;n++)
        acc[n] = __builtin_amdgcn_mfma_f32_16x16x32_bf16(afr[kt], wfrag[kt*4+n], acc[n], 0, 0, 0);
    }
    int tlb = (lane>>4)*4;
    #pragma unroll
    for(int n=0;n<4;n++){
      int h = n*16 + (lane&15);
      #pragma unroll
      for(int j=0;j<4;j++){
        float val = acc[n][j] + bias[n];
        ssum[n][j] += val; ssq[n][j] += val*val;
        Hout[(((size_t)b*T_ + t0 + tlb + j)*V_ + v)*64 + h] = f2b(val);
      }
    }
  }
  __syncthreads();   // Z free now

  // ---- cross-wave stat reduce: red[wave][2][16][64] in Z space ----
  float* red = (float*)Z;
  {
    int tlb = (lane>>4)*4;
    #pragma unroll
    for(int n=0;n<4;n++){
      int h = n*16 + (lane&15);
      #pragma unroll
      for(int j=0;j<4;j++){
        red[wid*2048 +        (tlb+j)*64 + h] = ssum[n][j];
        red[wid*2048 + 1024 + (tlb+j)*64 + h] = ssq[n][j];
      }
    }
  }
  __syncthreads();
  for(int i=tid; i<1024; i+=512){
    float s=0.f, q=0.f;
    #pragma unroll
    for(int w=0;w<8;w++){ s += red[w*2048 + i]; q += red[w*2048 + 1024 + i]; }
    atomicAdd(&sum2[t0*64 + i], s);
    atomicAdd(&sq2[t0*64 + i], q);
  }
}

// ---------------- conv1 via MFMA 32x32x16 bf16 ----------------
__device__ __forceinline__ bf16x8 loadH8(const bf16* H, int b, int v, int t0, int s){
  int ti = s>>3, h0 = (s&7)*8, t = t0-1+ti;
  bf16x8 r = {0,0,0,0,0,0,0,0};
  if(t >= 0 && t < T_) r = *(const bf16x8*)&H[(((size_t)b*T_+t)*V_ + v)*HD_ + h0];
  return r;
}

__device__ __forceinline__ void xform_store(short* zbuf, const unsigned int* sshf, int s, bf16x8 raw){
  int ti = s>>3, h0 = (s&7)*8;
  uint4 u0 = *(const uint4*)&sshf[ti*64 + h0];
  uint4 u1 = *(const uint4*)&sshf[ti*64 + h0 + 4];
  unsigned int uu[8] = {u0.x,u0.y,u0.z,u0.w,u1.x,u1.y,u1.z,u1.w};
  bf16x8 outv;
  #pragma unroll
  for(int j=0;j<8;j++){
    float scl = bits2f((unsigned short)(uu[j] & 0xffffu));
    float shf = bits2f((unsigned short)(uu[j] >> 16));
    float x = bits2f((unsigned short)raw[j]);
    outv[j] = (short)f2bits(fmaxf(x*scl + shf, 0.f));
  }
  *(bf16x8*)&zbuf[ti*72 + h0] = outv;
}

__global__ __launch_bounds__(256,2) void k_conv1(
    const bf16* __restrict__ H, const float* __restrict__ scale2, const float* __restrict__ shift2,
    const bf16* __restrict__ Wb, const float* __restrict__ c1b, float* __restrict__ C1)
{
  int b = blockIdx.y, t0 = blockIdx.x*64, tid = threadIdx.x;
  int lane = tid & 63, w = tid >> 6;
  __shared__ unsigned int sshf[66*64];
  __shared__ short zs[2][66*72];

  for(int i = tid; i < 66*64; i += 256){
    int ti = i>>6, h = i&63, t = t0-1+ti;
    unsigned int u = 0;
    if(t >= 0 && t < T_){
      u = ((unsigned)f2bits(shift2[t*64+h])<<16) | f2bits(scale2[t*64+h]);
    }
    sshf[i] = u;
  }
  __syncthreads();

  {
    bf16x8 a0 = loadH8(H,b,0,t0,tid);
    bf16x8 a1 = loadH8(H,b,0,t0,tid+256);
    bf16x8 a2 = {0,0,0,0,0,0,0,0};
    if(tid<16) a2 = loadH8(H,b,0,t0,tid+512);
    xform_store(zs[0], sshf, tid, a0);
    xform_store(zs[0], sshf, tid+256, a1);
    if(tid<16) xform_store(zs[0], sshf, tid+512, a2);
  }
  __syncthreads();

  int ow = w & 1, twv = (w>>1)*32;
  int o0 = ow*32;
  f32x16 acc = {};
  for(int v=0; v<25; v++){
    int cur = v & 1;
    bf16x8 a0={0,0,0,0,0,0,0,0}, a1={0,0,0,0,0,0,0,0}, a2={0,0,0,0,0,0,0,0};
    if(v < 24){
      a0 = loadH8(H,b,v+1,t0,tid);
      a1 = loadH8(H,b,v+1,t0,tid+256);
      if(tid<16) a2 = loadH8(H,b,v+1,t0,tid+512);
    }
    const short* zbuf = zs[cur];
    #pragma unroll
    for(int kc=0; kc<12; kc++){
      int ks = kc>>2;
      bf16x8 af = *(const bf16x8*)&Wb[((v*12+kc)*64 + o0 + (lane&31))*16 + (lane>>5)*8];
      int row = twv + (lane&31) + ks;
      int col = (kc&3)*16 + (lane>>5)*8;
      bf16x8 bfr = *(const bf16x8*)&zbuf[row*72 + col];
      acc = __builtin_amdgcn_mfma_f32_32x32x16_bf16(af, bfr, acc, 0, 0, 0);
    }
    if(v < 24){
      short* znext = zs[cur^1];
      xform_store(znext, sshf, tid, a0);
      xform_store(znext, sshf, tid+256, a1);
      if(tid<16) xform_store(znext, sshf, tid+512, a2);
    }
    __syncthreads();
  }
  int t = t0 + twv + (lane&31);
  #pragma unroll
  for(int r=0;r<16;r++){
    int o = o0 + (r&3) + 8*(r>>2) + 4*(lane>>5);
    C1[((size_t)b*64 + o)*T_ + t] = acc[r] + c1b[o];
  }
}

// ---------------- BN3 stats from C1 ----------------
__global__ __launch_bounds__(256) void k_stats3(const float* __restrict__ C1,
                                                float* __restrict__ sum3, float* __restrict__ sq3)
{
  int o = blockIdx.x, tid = threadIdx.x;
  float s=0.f, q=0.f;
  for(int idx = tid; idx < 64*128; idx += 256){
    int b = idx >> 7, t4 = idx & 127;
    float4 vv = *(const float4*)&C1[((size_t)(b*64+o))*T_ + t4*4];
    s += vv.x+vv.y+vv.z+vv.w;
    q += vv.x*vv.x + vv.y*vv.y + vv.z*vv.z + vv.w*vv.w;
  }
  __shared__ float rs[4], rq[4];
  for(int off=32; off; off>>=1){ s += __shfl_down(s, off); q += __shfl_down(q, off); }
  if((tid&63)==0){ rs[tid>>6]=s; rq[tid>>6]=q; }
  __syncthreads();
  if(tid==0){ sum3[o] = rs[0]+rs[1]+rs[2]+rs[3]; sq3[o] = rq[0]+rq[1]+rq[2]+rq[3]; }
}

// ---------------- per-channel BN finalize ----------------
__global__ void k_bnfin_ch(const float* __restrict__ sum, const float* __restrict__ sq,
                           const float* __restrict__ g, const float* __restrict__ bt,
                           float* __restrict__ scale, float* __restrict__ shift,
                           int nch, float inv_count)
{
  int i = blockIdx.x*blockDim.x + threadIdx.x;
  if(i < nch){
    float m = sum[i]*inv_count;
    float v = sq[i]*inv_count - m*m;
    float r = rsqrtf(fmaxf(v, 0.f) + 1e-5f);
    float sc = g[i]*r;
    scale[i]=sc; shift[i]=bt[i]-m*sc;
  }
}

// ---------------- conv2 ----------------
__global__ __launch_bounds__(256) void k_conv2(
    const float* __restrict__ C1, const float* __restrict__ scale3, const float* __restrict__ shift3,
    const float* __restrict__ c2Wt, const float* __restrict__ c2b,
    float* __restrict__ C2, float* __restrict__ sum4, float* __restrict__ sq4)
{
  int b = blockIdx.y, t0 = blockIdx.x*64, tid = threadIdx.x;
  __shared__ float z[64][69];
  __shared__ float scl[64], shf[64];
  __shared__ float ps[128][9], pq[128][9];
  if(tid < 64){ scl[tid]=scale3[tid]; shf[tid]=shift3[tid]; }
  __syncthreads();
  for(int i=tid; i<64*68; i+=256){
    int ti = i % 68, ci = i / 68;
    int t = t0 - 2 + ti;
    float val = 0.f;
    if(t >= 0 && t < T_){
      val = fmaxf(C1[((size_t)b*64+ci)*T_ + t]*scl[ci] + shf[ci], 0.f);
    }
    z[ci][ti] = val;
  }
  __syncthreads();
  int og = tid & 31, tg = tid >> 5;
  int o0 = og*4;
  float acc[8][4];
  #pragma unroll
  for(int i=0;i<8;i++){
    #pragma unroll
    for(int j=0;j<4;j++) acc[i][j]=0.f;
  }
  for(int ci=0; ci<64; ci++){
    float4 w0 = *(const float4*)&c2Wt[0*8192 + ci*128 + o0];
    float4 w1 = *(const float4*)&c2Wt[1*8192 + ci*128 + o0];
    float4 w2 = *(const float4*)&c2Wt[2*8192 + ci*128 + o0];
    float zr[12];
    #pragma unroll
    for(int j=0;j<12;j++) zr[j] = z[ci][tg*8 + j];
    #pragma unroll
    for(int tt=0;tt<8;tt++){
      float z0=zr[tt], z1=zr[tt+2], z2=zr[tt+4];
      acc[tt][0] += w0.x*z0 + w1.x*z1 + w2.x*z2;
      acc[tt][1] += w0.y*z0 + w1.y*z1 + w2.y*z2;
      acc[tt][2] += w0.z*z0 + w1.z*z1 + w2.z*z2;
      acc[tt][3] += w0.w*z0 + w1.w*z1 + w2.w*z2;
    }
  }
  #pragma unroll
  for(int oo=0;oo<4;oo++){
    float bsv = c2b[o0+oo];
    float s=0.f, q=0.f;
    #pragma unroll
    for(int tt=0;tt<8;tt++){
      float y = acc[tt][oo] + bsv;
      C2[((size_t)b*128 + o0+oo)*T_ + t0 + tg*8 + tt] = y;
      s += y; q += y*y;
    }
    ps[o0+oo][tg]=s; pq[o0+oo][tg]=q;
  }
  __syncthreads();
  if(tid < 128){
    float s=0.f, q=0.f;
    for(int g=0; g<8; g++){ s+=ps[tid][g]; q+=pq[tid][g]; }
    atomicAdd(&sum4[tid], s); atomicAdd(&sq4[tid], q);
  }
}

// ---------------- head ----------------
__global__ __launch_bounds__(256) void k_head(
    const float* __restrict__ C2, const float* __restrict__ scale4, const float* __restrict__ shift4,
    const float* __restrict__ fcW, const float* __restrict__ fcb, float* __restrict__ out)
{
  int b = blockIdx.x, tid = threadIdx.x;
  __shared__ float mean[128];
  __shared__ float ms[256];
  int ch = tid >> 1, p = tid & 1;
  float scl = scale4[ch], shf = shift4[ch];
  const float* src = C2 + ((size_t)b*128 + ch)*T_ + p*256;
  float s = 0.f;
  for(int i=0;i<256;i++){
    s += fmaxf(src[i]*scl + shf, 0.f);
  }
  ms[tid] = s;
  __syncthreads();
  if(tid < 128) mean[tid] = (ms[2*tid] + ms[2*tid+1]) * (1.0f/512.0f);
  __syncthreads();
  if(tid < NC_){
    float acc = fcb[tid];
    for(int c=0;c<128;c++) acc += mean[c]*fcW[c*NC_ + tid];
    out[b*NC_ + tid] = acc;
  }
}

// ---------------- launch ----------------
extern "C" void kernel_launch(void* const* d_in, const int* in_sizes, int n_in,
                              void* d_out, int out_size, void* d_ws, size_t ws_size,
                              hipStream_t stream)
{
  const float* X   = (const float*)d_in[0];
  const int*   ei  = (const int*)  d_in[1];
  const float* W1  = (const float*)d_in[2];
  const float* s1W = (const float*)d_in[3];
  const float* s1b = (const float*)d_in[4];
  const float* g1  = (const float*)d_in[5];
  const float* b1  = (const float*)d_in[6];
  const float* W2  = (const float*)d_in[7];
  const float* s2W = (const float*)d_in[8];
  const float* s2b = (const float*)d_in[9];
  const float* g2  = (const float*)d_in[10];
  const float* b2  = (const float*)d_in[11];
  const float* c1W = (const float*)d_in[12];
  const float* c1b = (const float*)d_in[13];
  const float* tg1 = (const float*)d_in[14];
  const float* tb1 = (const float*)d_in[15];
  const float* c2W = (const float*)d_in[16];
  const float* c2b = (const float*)d_in[17];
  const float* tg2 = (const float*)d_in[18];
  const float* tb2 = (const float*)d_in[19];
  const float* fcW = (const float*)d_in[20];
  const float* fcb = (const float*)d_in[21];

  char* ws = (char*)d_ws;
  bf16*  H     = (bf16*) (ws);                       // 104,857,600 B
  float* C1    = (float*)(ws + 104857600);
  float* C2    = (float*)(ws + 113246208);
  bf16*  Wb    = (bf16*) (ws + 130023424);           // conv1 A-frag weights
  float* c2Wt  = (float*)(ws + 131252224);
  bf16*  WbB   = (bf16*) (ws + 131350528);           // gcn2 B-frag weights (16,384 B)
  float* stats = (float*)(ws + 131366912);
  float* sum1 = stats;            float* sq1 = stats + 32768;
  float* sum2 = stats + 65536;    float* sq2 = stats + 98304;
  float* sum3 = stats + 131072;   float* sq3 = sum3 + 64;
  float* sum4 = sq3 + 64;         float* sq4 = sum4 + 128;
  float* scale1 = stats + 131456; float* shift1 = scale1 + 32768;
  float* scale2 = shift1 + 32768; float* shift2 = scale2 + 32768;
  float* scale3 = shift2 + 32768; float* shift3 = scale3 + 64;
  float* scale4 = shift3 + 64;    float* shift4 = scale4 + 128;
  int* csr_off = (int*)(shift4 + 128);
  int* csr_lst = csr_off + 32;

  hipMemsetAsync(stats, 0, (size_t)131456*sizeof(float), stream);
  k_csr<<<1, 64, 0, stream>>>(ei, csr_off, csr_lst);
  k_wt<<<256, 256, 0, stream>>>(c1W, c2W, s2W, W2, Wb, c2Wt, WbB);

  k_gcn1<<<dim3(T_, B_), 256, 0, stream>>>(X, s1W, W1, s1b, csr_off, csr_lst, H, sum1, sq1);
  k_bnfin_th<<<128, 256, 0, stream>>>(sum1, sq1, g1, b1, scale1, shift1);
  k_gcn2<<<dim3(T_/16, B_), 512, 0, stream>>>(H, H, scale1, shift1, WbB, s2b, csr_off, csr_lst, sum2, sq2);
  k_bnfin_th<<<128, 256, 0, stream>>>(sum2, sq2, g2, b2, scale2, shift2);
  k_conv1<<<dim3(8, B_), 256, 0, stream>>>(H, scale2, shift2, Wb, c1b, C1);
  k_stats3<<<64, 256, 0, stream>>>(C1, sum3, sq3);
  k_bnfin_ch<<<1, 64, 0, stream>>>(sum3, sq3, tg1, tb1, scale3, shift3, 64, 1.0f/32768.0f);
  k_conv2<<<dim3(8, B_), 256, 0, stream>>>(C1, scale3, shift3, c2Wt, c2b, C2, sum4, sq4);
  k_bnfin_ch<<<1, 128, 0, stream>>>(sum4, sq4, tg2, tb2, scale4, shift4, 128, 1.0f/32768.0f);
  k_head<<<B_, 256, 0, stream>>>(C2, scale4, shift4, fcW, fcb, (float*)d_out);
}

// Round 4
// 319.183 us; speedup vs baseline: 3.8100x; 1.0508x over previous
//
#include <hip/hip_runtime.h>
#include <hip/hip_bf16.h>
#include <cstddef>

using bf16 = __hip_bfloat16;
typedef __attribute__((ext_vector_type(8)))  short bf16x8;
typedef __attribute__((ext_vector_type(4)))  float f32x4;
typedef __attribute__((ext_vector_type(16))) float f32x16;

#define B_   64
#define T_   512
#define V_   25
#define HD_  64
#define E_   48
#define NC_  60

__device__ __forceinline__ float b2f(bf16 x){ return __bfloat162float(x); }
__device__ __forceinline__ bf16  f2b(float x){ return __float2bfloat16(x); }
__device__ __forceinline__ unsigned short f2bits(float x){ return __builtin_bit_cast(unsigned short, f2b(x)); }
__device__ __forceinline__ float bits2f(unsigned short s){ return __builtin_bit_cast(float, ((unsigned)s)<<16); }

// ---------------- prep: CSR of edges grouped by dst ----------------
__global__ void k_csr(const int* __restrict__ ei, int* __restrict__ offs, int* __restrict__ lst)
{
  int tid = threadIdx.x;
  if(tid == 0){
    int cnt[V_], pos[V_];
    for(int v=0;v<V_;v++) cnt[v]=0;
    for(int e=0;e<E_;e++) cnt[ei[2*e+1]]++;
    int off = 0;
    for(int v=0;v<V_;v++){ offs[v]=off; pos[v]=off; off+=cnt[v]; }
    offs[V_] = off;
    for(int e=0;e<E_;e++){ int d = ei[2*e+1]; lst[pos[d]++] = ei[2*e+0]; }
  }
}

// ---------------- prep: weight packing ----------------
__global__ void k_wt(const float* __restrict__ c1W, const float* __restrict__ c2W,
                     const float* __restrict__ s2W, const float* __restrict__ W2,
                     bf16* __restrict__ Wb, float* __restrict__ c2Wt, bf16* __restrict__ WbB)
{
  int i0 = blockIdx.x*blockDim.x + threadIdx.x, stride = gridDim.x*blockDim.x;
  for(int i = i0; i < 307200; i += stride){
    int hlo = i & 15, o = (i>>4)&63, kc = (i>>10)%12, v = i/12288;
    int ks = kc>>2, h = (kc&3)*16 + hlo;
    Wb[i] = f2b(c1W[(o*1600 + v*64 + h)*3 + ks]);
  }
  for(int i = i0; i < 24576; i += stride){
    int o = i & 127, ci = (i>>7)&63, k = i >> 13;
    c2Wt[i] = c2W[(o*64+ci)*3 + k];
  }
  for(int i = i0; i < 8192; i += stride){
    int j = i&7, l=(i>>3)&63, n=(i>>9)&3, kt=i>>11;
    int k = kt*32 + (l>>4)*8 + j;
    int h = n*16 + (l&15);
    float val = (k < 64) ? s2W[k*64 + h] : W2[(k-64)*64 + h];
    WbB[i] = f2b(val);
  }
}

// ---------------- GCN layer 1 ----------------
__global__ __launch_bounds__(256) void k_gcn1(
    const float* __restrict__ X, const float* __restrict__ s1W, const float* __restrict__ W1,
    const float* __restrict__ s1b, const int* __restrict__ offs, const int* __restrict__ lst,
    bf16* __restrict__ H, float* __restrict__ sum1, float* __restrict__ sq1)
{
  int t = blockIdx.x, b = blockIdx.y, tid = threadIdx.x;
  __shared__ float Xs[V_][4];
  __shared__ float ag[V_][4];
  __shared__ float sw[3][64], gw[3][64], bias[64];
  __shared__ int so[V_+1], sl[E_];
  __shared__ float ps[4][64], pq[4][64];
  if(tid < 192){ sw[tid/64][tid&63] = s1W[tid]; gw[tid/64][tid&63] = W1[tid]; }
  if(tid < 64) bias[tid] = s1b[tid];
  if(tid < V_+1) so[tid] = offs[tid];
  if(tid < E_) sl[tid] = lst[tid];
  if(tid < 75){ int c = tid/25, v = tid%25; Xs[v][c] = X[((size_t)(b*3+c)*T_ + t)*V_ + v]; }
  __syncthreads();
  if(tid < 75){
    int v = tid/3, c = tid%3;
    float s = 0.f;
    for(int e=so[v]; e<so[v+1]; e++) s += Xs[sl[e]][c];
    ag[v][c] = s;
  }
  __syncthreads();
  int h = tid & 63, vg = tid >> 6;
  float lsum = 0.f, lsq = 0.f;
  for(int v=vg; v<V_; v+=4){
    float acc = bias[h];
    for(int c=0;c<3;c++) acc += Xs[v][c]*sw[c][h] + ag[v][c]*gw[c][h];
    H[(((size_t)b*T_+t)*V_+v)*HD_ + h] = f2b(acc);
    lsum += acc; lsq += acc*acc;
  }
  ps[vg][h]=lsum; pq[vg][h]=lsq;
  __syncthreads();
  if(vg == 0){
    float s = ps[0][h]+ps[1][h]+ps[2][h]+ps[3][h];
    float q = pq[0][h]+pq[1][h]+pq[2][h]+pq[3][h];
    atomicAdd(&sum1[t*HD_+h], s);
    atomicAdd(&sq1[t*HD_+h], q);
  }
}

// ---------------- per-(t,h) BN finalize ----------------
__global__ void k_bnfin_th(const float* __restrict__ sum, const float* __restrict__ sq,
                           const float* __restrict__ g, const float* __restrict__ bt,
                           float* __restrict__ scale, float* __restrict__ shift)
{
  int i = blockIdx.x*blockDim.x + threadIdx.x;
  if(i < T_*HD_){
    int h = i & 63;
    float m = sum[i] * (1.0f/1600.0f);
    float v = sq[i] * (1.0f/1600.0f) - m*m;
    float r = rsqrtf(fmaxf(v, 0.f) + 1e-5f);
    float sc = g[h]*r;
    scale[i] = sc;
    shift[i] = bt[h] - m*sc;
  }
}

// ---------------- GCN layer 2 via MFMA 16x16x32 (in-place on H) ----------------
__global__ __launch_bounds__(512,2) void k_gcn2(
    const bf16* Hin, bf16* Hout,   // same pointer
    const float* __restrict__ scale1, const float* __restrict__ shift1,
    const bf16* __restrict__ WbB, const float* __restrict__ s2b,
    const int* __restrict__ offs, const int* __restrict__ lst,
    float* __restrict__ sum2, float* __restrict__ sq2)
{
  int tid = threadIdx.x, lane = tid & 63, wid = tid >> 6;
  int b = blockIdx.y, t0 = blockIdx.x*16;
  __shared__ short Z[400*136];      // 108,800 B
  __shared__ float scl[1024], shf[1024];
  __shared__ int so[V_+1], sl[E_];

  bf16x8 wfrag[16];
  #pragma unroll
  for(int i=0;i<16;i++) wfrag[i] = *(const bf16x8*)&WbB[(i*64 + lane)*8];
  float bias[4];
  #pragma unroll
  for(int n=0;n<4;n++) bias[n] = s2b[n*16 + (lane&15)];

  if(tid < V_+1) so[tid]=offs[tid];
  if(tid >= 64 && tid < 64+E_) sl[tid-64]=lst[tid-64];
  for(int i=tid; i<1024; i+=512){
    scl[i] = scale1[t0*64 + i];
    shf[i] = shift1[t0*64 + i];
  }
  __syncthreads();

  // stage Hn = relu(bn1(H)) into Z[:, 0:64]
  const bf16* hbase = Hin + ((size_t)b*T_ + t0)*V_*64;
  for(int c=tid; c<3200; c+=512){
    int h8 = c & 7, rr = c >> 3;          // rr = t_local*25 + v
    int tl = rr/25, v = rr - tl*25;
    bf16x8 raw = *(const bf16x8*)&hbase[(size_t)rr*64 + h8*8];
    float4 s0 = *(const float4*)&scl[tl*64 + h8*8];
    float4 s1 = *(const float4*)&scl[tl*64 + h8*8 + 4];
    float4 f0 = *(const float4*)&shf[tl*64 + h8*8];
    float4 f1 = *(const float4*)&shf[tl*64 + h8*8 + 4];
    float sv[8] = {s0.x,s0.y,s0.z,s0.w,s1.x,s1.y,s1.z,s1.w};
    float fv[8] = {f0.x,f0.y,f0.z,f0.w,f1.x,f1.y,f1.z,f1.w};
    bf16x8 o;
    #pragma unroll
    for(int j=0;j<8;j++){
      float x = bits2f((unsigned short)raw[j])*sv[j] + fv[j];
      o[j] = (short)f2bits(fmaxf(x, 0.f));
    }
    *(bf16x8*)&Z[(v*16 + tl)*136 + h8*8] = o;
  }
  __syncthreads();

  // aggregate neighbors into Z[:, 64:128]
  for(int c=tid; c<3200; c+=512){
    int h8 = c & 7, r = c >> 3;           // r = v*16 + t_local
    int v = r >> 4, tl = r & 15;
    float accv[8];
    #pragma unroll
    for(int j=0;j<8;j++) accv[j] = 0.f;
    for(int e=so[v]; e<so[v+1]; e++){
      int u = sl[e];
      bf16x8 nb = *(const bf16x8*)&Z[(u*16 + tl)*136 + h8*8];
      #pragma unroll
      for(int j=0;j<8;j++) accv[j] += bits2f((unsigned short)nb[j]);
    }
    bf16x8 o;
    #pragma unroll
    for(int j=0;j<8;j++) o[j] = (short)f2bits(accv[j]);
    *(bf16x8*)&Z[r*136 + 64 + h8*8] = o;
  }
  __syncthreads();

  // MFMA: wave wid handles v = wid, wid+8, wid+16, wid+24; acc kept in regs
  f32x4 accs[4][4] = {};
  #pragma unroll
  for(int vi=0; vi<4; vi++){
    int v = wid + vi*8;
    if(v < V_){
      bf16x8 afr[4];
      #pragma unroll
      for(int kt=0;kt<4;kt++)
        afr[kt] = *(const bf16x8*)&Z[(v*16 + (lane&15))*136 + kt*32 + (lane>>4)*8];
      #pragma unroll
      for(int kt=0;kt<4;kt++){
        #pragma unroll
        for(int n=0;n<4;n++)
          accs[vi][n] = __builtin_amdgcn_mfma_f32_16x16x32_bf16(afr[kt], wfrag[kt*4+n], accs[vi][n], 0, 0, 0);
      }
    }
  }
  __syncthreads();   // all Z reads done

  // write C frags (bf16) into LDS, rr-major, row stride 72 shorts
  short* Cs = Z;
  int tlb = (lane>>4)*4;
  f32x4 ssum[4] = {}, ssq[4] = {};
  #pragma unroll
  for(int vi=0; vi<4; vi++){
    int v = wid + vi*8;
    if(v < V_){
      #pragma unroll
      for(int n=0;n<4;n++){
        int h = n*16 + (lane&15);
        #pragma unroll
        for(int j=0;j<4;j++){
          float val = accs[vi][n][j] + bias[n];
          ssum[n][j] += val; ssq[n][j] += val*val;
          Cs[((tlb+j)*25 + v)*72 + h] = (short)f2bits(val);
        }
      }
    }
  }
  __syncthreads();

  // cooperative contiguous bf16x8 store of the whole 16t x 25v x 64h tile
  bf16* hbout = Hout + ((size_t)b*T_ + t0)*V_*64;
  for(int c=tid; c<3200; c+=512){
    bf16x8 o = *(const bf16x8*)&Cs[(c>>3)*72 + (c&7)*8];
    *(bf16x8*)&hbout[(size_t)c*8] = o;
  }
  __syncthreads();

  // cross-wave stat reduce
  float* red = (float*)Z;
  {
    #pragma unroll
    for(int n=0;n<4;n++){
      int h = n*16 + (lane&15);
      #pragma unroll
      for(int j=0;j<4;j++){
        red[wid*2048 +        (tlb+j)*64 + h] = ssum[n][j];
        red[wid*2048 + 1024 + (tlb+j)*64 + h] = ssq[n][j];
      }
    }
  }
  __syncthreads();
  for(int i=tid; i<1024; i+=512){
    float s=0.f, q=0.f;
    #pragma unroll
    for(int w=0;w<8;w++){ s += red[w*2048 + i]; q += red[w*2048 + 1024 + i]; }
    atomicAdd(&sum2[t0*64 + i], s);
    atomicAdd(&sq2[t0*64 + i], q);
  }
}

// ---------------- conv1 via MFMA, K-split over 2 v-groups ----------------
__device__ __forceinline__ bf16x8 loadH8(const bf16* H, int b, int v, int t0, int s){
  int ti = s>>3, h0 = (s&7)*8, t = t0-1+ti;
  bf16x8 r = {0,0,0,0,0,0,0,0};
  if(t >= 0 && t < T_) r = *(const bf16x8*)&H[(((size_t)b*T_+t)*V_ + v)*HD_ + h0];
  return r;
}

__device__ __forceinline__ void xform_store(short* zbuf, const unsigned int* sshf, int s, bf16x8 raw){
  int ti = s>>3, h0 = (s&7)*8;
  uint4 u0 = *(const uint4*)&sshf[ti*64 + h0];
  uint4 u1 = *(const uint4*)&sshf[ti*64 + h0 + 4];
  unsigned int uu[8] = {u0.x,u0.y,u0.z,u0.w,u1.x,u1.y,u1.z,u1.w};
  bf16x8 outv;
  #pragma unroll
  for(int j=0;j<8;j++){
    float scl = bits2f((unsigned short)(uu[j] & 0xffffu));
    float shf = bits2f((unsigned short)(uu[j] >> 16));
    float x = bits2f((unsigned short)raw[j]);
    outv[j] = (short)f2bits(fmaxf(x*scl + shf, 0.f));
  }
  *(bf16x8*)&zbuf[ti*72 + h0] = outv;
}

__global__ __launch_bounds__(256,4) void k_conv1(
    const bf16* __restrict__ H, const float* __restrict__ scale2, const float* __restrict__ shift2,
    const bf16* __restrict__ Wb, float* __restrict__ P)
{
  int b = blockIdx.y, t0 = blockIdx.x*64, vg = blockIdx.z, tid = threadIdx.x;
  int lane = tid & 63, w = tid >> 6;
  int v0 = vg ? 13 : 0, nv = vg ? 12 : 13;
  __shared__ unsigned int sshf[66*64];
  __shared__ short zs[2][66*72];

  for(int i = tid; i < 66*64; i += 256){
    int ti = i>>6, h = i&63, t = t0-1+ti;
    unsigned int u = 0;
    if(t >= 0 && t < T_){
      u = ((unsigned)f2bits(shift2[t*64+h])<<16) | f2bits(scale2[t*64+h]);
    }
    sshf[i] = u;
  }
  __syncthreads();

  {
    bf16x8 a0 = loadH8(H,b,v0,t0,tid);
    bf16x8 a1 = loadH8(H,b,v0,t0,tid+256);
    bf16x8 a2 = {0,0,0,0,0,0,0,0};
    if(tid<16) a2 = loadH8(H,b,v0,t0,tid+512);
    xform_store(zs[0], sshf, tid, a0);
    xform_store(zs[0], sshf, tid+256, a1);
    if(tid<16) xform_store(zs[0], sshf, tid+512, a2);
  }
  __syncthreads();

  int ow = w & 1, twv = (w>>1)*32;
  int o0 = ow*32;
  f32x16 acc = {};
  for(int i=0; i<nv; i++){
    int v = v0 + i, cur = i & 1;
    bf16x8 a0={0,0,0,0,0,0,0,0}, a1={0,0,0,0,0,0,0,0}, a2={0,0,0,0,0,0,0,0};
    if(i+1 < nv){
      a0 = loadH8(H,b,v+1,t0,tid);
      a1 = loadH8(H,b,v+1,t0,tid+256);
      if(tid<16) a2 = loadH8(H,b,v+1,t0,tid+512);
    }
    const short* zbuf = zs[cur];
    #pragma unroll
    for(int kc=0; kc<12; kc++){
      int ks = kc>>2;
      bf16x8 af = *(const bf16x8*)&Wb[((v*12+kc)*64 + o0 + (lane&31))*16 + (lane>>5)*8];
      int row = twv + (lane&31) + ks;
      int col = (kc&3)*16 + (lane>>5)*8;
      bf16x8 bfr = *(const bf16x8*)&zbuf[row*72 + col];
      acc = __builtin_amdgcn_mfma_f32_32x32x16_bf16(af, bfr, acc, 0, 0, 0);
    }
    if(i+1 < nv){
      short* znext = zs[cur^1];
      xform_store(znext, sshf, tid, a0);
      xform_store(znext, sshf, tid+256, a1);
      if(tid<16) xform_store(znext, sshf, tid+512, a2);
    }
    __syncthreads();
  }
  int t = t0 + twv + (lane&31);
  size_t pbase = ((size_t)vg*B_ + b)*64;
  #pragma unroll
  for(int r=0;r<16;r++){
    int o = o0 + (r&3) + 8*(r>>2) + 4*(lane>>5);
    P[(pbase + o)*T_ + t] = acc[r];
  }
}

// ---------------- reduce partial planes -> C1 (+bias) and BN3 stats ----------------
__global__ __launch_bounds__(128) void k_red1(
    const float* __restrict__ P, const float* __restrict__ c1b,
    float* __restrict__ C1, float* __restrict__ sum3, float* __restrict__ sq3)
{
  int o = blockIdx.x, b = blockIdx.y, tid = threadIdx.x;
  size_t base = ((size_t)b*64 + o)*T_ + tid*4;
  float4 x = *(const float4*)&P[base];
  float4 y = *(const float4*)&P[2097152 + base];
  float bias = c1b[o];
  float4 r;
  r.x = x.x + y.x + bias; r.y = x.y + y.y + bias;
  r.z = x.z + y.z + bias; r.w = x.w + y.w + bias;
  *(float4*)&C1[base] = r;
  float s = r.x + r.y + r.z + r.w;
  float q = r.x*r.x + r.y*r.y + r.z*r.z + r.w*r.w;
  for(int off=32; off; off>>=1){ s += __shfl_down(s, off); q += __shfl_down(q, off); }
  __shared__ float rs[2], rq[2];
  if((tid&63)==0){ rs[tid>>6]=s; rq[tid>>6]=q; }
  __syncthreads();
  if(tid==0){ atomicAdd(&sum3[o], rs[0]+rs[1]); atomicAdd(&sq3[o], rq[0]+rq[1]); }
}

// ---------------- per-channel BN finalize ----------------
__global__ void k_bnfin_ch(const float* __restrict__ sum, const float* __restrict__ sq,
                           const float* __restrict__ g, const float* __restrict__ bt,
                           float* __restrict__ scale, float* __restrict__ shift,
                           int nch, float inv_count)
{
  int i = blockIdx.x*blockDim.x + threadIdx.x;
  if(i < nch){
    float m = sum[i]*inv_count;
    float v = sq[i]*inv_count - m*m;
    float r = rsqrtf(fmaxf(v, 0.f) + 1e-5f);
    float sc = g[i]*r;
    scale[i]=sc; shift[i]=bt[i]-m*sc;
  }
}

// ---------------- conv2 ----------------
__global__ __launch_bounds__(256) void k_conv2(
    const float* __restrict__ C1, const float* __restrict__ scale3, const float* __restrict__ shift3,
    const float* __restrict__ c2Wt, const float* __restrict__ c2b,
    float* __restrict__ C2, float* __restrict__ sum4, float* __restrict__ sq4)
{
  int b = blockIdx.y, t0 = blockIdx.x*64, tid = threadIdx.x;
  __shared__ float z[64][69];
  __shared__ float scl[64], shf[64];
  __shared__ float ps[128][9], pq[128][9];
  if(tid < 64){ scl[tid]=scale3[tid]; shf[tid]=shift3[tid]; }
  __syncthreads();
  for(int i=tid; i<64*68; i+=256){
    int ti = i % 68, ci = i / 68;
    int t = t0 - 2 + ti;
    float val = 0.f;
    if(t >= 0 && t < T_){
      val = fmaxf(C1[((size_t)b*64+ci)*T_ + t]*scl[ci] + shf[ci], 0.f);
    }
    z[ci][ti] = val;
  }
  __syncthreads();
  int og = tid & 31, tg = tid >> 5;
  int o0 = og*4;
  float acc[8][4];
  #pragma unroll
  for(int i=0;i<8;i++){
    #pragma unroll
    for(int j=0;j<4;j++) acc[i][j]=0.f;
  }
  for(int ci=0; ci<64; ci++){
    float4 w0 = *(const float4*)&c2Wt[0*8192 + ci*128 + o0];
    float4 w1 = *(const float4*)&c2Wt[1*8192 + ci*128 + o0];
    float4 w2 = *(const float4*)&c2Wt[2*8192 + ci*128 + o0];
    float zr[12];
    #pragma unroll
    for(int j=0;j<12;j++) zr[j] = z[ci][tg*8 + j];
    #pragma unroll
    for(int tt=0;tt<8;tt++){
      float z0=zr[tt], z1=zr[tt+2], z2=zr[tt+4];
      acc[tt][0] += w0.x*z0 + w1.x*z1 + w2.x*z2;
      acc[tt][1] += w0.y*z0 + w1.y*z1 + w2.y*z2;
      acc[tt][2] += w0.z*z0 + w1.z*z1 + w2.z*z2;
      acc[tt][3] += w0.w*z0 + w1.w*z1 + w2.w*z2;
    }
  }
  #pragma unroll
  for(int oo=0;oo<4;oo++){
    float bsv = c2b[o0+oo];
    float s=0.f, q=0.f;
    #pragma unroll
    for(int tt=0;tt<8;tt++){
      float y = acc[tt][oo] + bsv;
      C2[((size_t)b*128 + o0+oo)*T_ + t0 + tg*8 + tt] = y;
      s += y; q += y*y;
    }
    ps[o0+oo][tg]=s; pq[o0+oo][tg]=q;
  }
  __syncthreads();
  if(tid < 128){
    float s=0.f, q=0.f;
    for(int g=0; g<8; g++){ s+=ps[tid][g]; q+=pq[tid][g]; }
    atomicAdd(&sum4[tid], s); atomicAdd(&sq4[tid], q);
  }
}

// ---------------- head ----------------
__global__ __launch_bounds__(256) void k_head(
    const float* __restrict__ C2, const float* __restrict__ scale4, const float* __restrict__ shift4,
    const float* __restrict__ fcW, const float* __restrict__ fcb, float* __restrict__ out)
{
  int b = blockIdx.x, tid = threadIdx.x;
  __shared__ float mean[128];
  __shared__ float ms[256];
  int ch = tid >> 1, p = tid & 1;
  float scl = scale4[ch], shf = shift4[ch];
  const float* src = C2 + ((size_t)b*128 + ch)*T_ + p*256;
  float s = 0.f;
  for(int i=0;i<256;i++){
    s += fmaxf(src[i]*scl + shf, 0.f);
  }
  ms[tid] = s;
  __syncthreads();
  if(tid < 128) mean[tid] = (ms[2*tid] + ms[2*tid+1]) * (1.0f/512.0f);
  __syncthreads();
  if(tid < NC_){
    float acc = fcb[tid];
    for(int c=0;c<128;c++) acc += mean[c]*fcW[c*NC_ + tid];
    out[b*NC_ + tid] = acc;
  }
}

// ---------------- launch ----------------
extern "C" void kernel_launch(void* const* d_in, const int* in_sizes, int n_in,
                              void* d_out, int out_size, void* d_ws, size_t ws_size,
                              hipStream_t stream)
{
  const float* X   = (const float*)d_in[0];
  const int*   ei  = (const int*)  d_in[1];
  const float* W1  = (const float*)d_in[2];
  const float* s1W = (const float*)d_in[3];
  const float* s1b = (const float*)d_in[4];
  const float* g1  = (const float*)d_in[5];
  const float* b1  = (const float*)d_in[6];
  const float* W2  = (const float*)d_in[7];
  const float* s2W = (const float*)d_in[8];
  const float* s2b = (const float*)d_in[9];
  const float* g2  = (const float*)d_in[10];
  const float* b2  = (const float*)d_in[11];
  const float* c1W = (const float*)d_in[12];
  const float* c1b = (const float*)d_in[13];
  const float* tg1 = (const float*)d_in[14];
  const float* tb1 = (const float*)d_in[15];
  const float* c2W = (const float*)d_in[16];
  const float* c2b = (const float*)d_in[17];
  const float* tg2 = (const float*)d_in[18];
  const float* tb2 = (const float*)d_in[19];
  const float* fcW = (const float*)d_in[20];
  const float* fcb = (const float*)d_in[21];

  char* ws = (char*)d_ws;
  bf16*  H     = (bf16*) (ws);                       // 104,857,600 B
  float* C1    = (float*)(ws + 104857600);           // 8 MB
  float* C2    = (float*)(ws + 113246208);           // 16 MB (also conv1 partial planes)
  float* P     = C2;                                  // alias: used before conv2 writes C2
  bf16*  Wb    = (bf16*) (ws + 130023424);
  float* c2Wt  = (float*)(ws + 131252224);
  bf16*  WbB   = (bf16*) (ws + 131350528);
  float* stats = (float*)(ws + 131366912);
  float* sum1 = stats;            float* sq1 = stats + 32768;
  float* sum2 = stats + 65536;    float* sq2 = stats + 98304;
  float* sum3 = stats + 131072;   float* sq3 = sum3 + 64;
  float* sum4 = sq3 + 64;         float* sq4 = sum4 + 128;
  float* scale1 = stats + 131456; float* shift1 = scale1 + 32768;
  float* scale2 = shift1 + 32768; float* shift2 = scale2 + 32768;
  float* scale3 = shift2 + 32768; float* shift3 = scale3 + 64;
  float* scale4 = shift3 + 64;    float* shift4 = scale4 + 128;
  int* csr_off = (int*)(shift4 + 128);
  int* csr_lst = csr_off + 32;

  hipMemsetAsync(stats, 0, (size_t)131456*sizeof(float), stream);
  k_csr<<<1, 64, 0, stream>>>(ei, csr_off, csr_lst);
  k_wt<<<256, 256, 0, stream>>>(c1W, c2W, s2W, W2, Wb, c2Wt, WbB);

  k_gcn1<<<dim3(T_, B_), 256, 0, stream>>>(X, s1W, W1, s1b, csr_off, csr_lst, H, sum1, sq1);
  k_bnfin_th<<<128, 256, 0, stream>>>(sum1, sq1, g1, b1, scale1, shift1);
  k_gcn2<<<dim3(T_/16, B_), 512, 0, stream>>>(H, H, scale1, shift1, WbB, s2b, csr_off, csr_lst, sum2, sq2);
  k_bnfin_th<<<128, 256, 0, stream>>>(sum2, sq2, g2, b2, scale2, shift2);
  k_conv1<<<dim3(8, B_, 2), 256, 0, stream>>>(H, scale2, shift2, Wb, P);
  k_red1<<<dim3(64, B_), 128, 0, stream>>>(P, c1b, C1, sum3, sq3);
  k_bnfin_ch<<<1, 64, 0, stream>>>(sum3, sq3, tg1, tb1, scale3, shift3, 64, 1.0f/32768.0f);
  k_conv2<<<dim3(8, B_), 256, 0, stream>>>(C1, scale3, shift3, c2Wt, c2b, C2, sum4, sq4);
  k_bnfin_ch<<<1, 128, 0, stream>>>(sum4, sq4, tg2, tb2, scale4, shift4, 128, 1.0f/32768.0f);
  k_head<<<B_, 256, 0, stream>>>(C2, scale4, shift4, fcW, fcb, (float*)d_out);
}

// Round 5
// 299.318 us; speedup vs baseline: 4.0629x; 1.0664x over previous
//
#include <hip/hip_runtime.h>
#include <hip/hip_bf16.h>
#include <cstddef>

using bf16 = __hip_bfloat16;
typedef __attribute__((ext_vector_type(8)))  short bf16x8;
typedef __attribute__((ext_vector_type(4)))  float f32x4;
typedef __attribute__((ext_vector_type(16))) float f32x16;

#define B_   64
#define T_   512
#define V_   25
#define HD_  64
#define E_   48
#define NC_  60

__device__ __forceinline__ float b2f(bf16 x){ return __bfloat162float(x); }
__device__ __forceinline__ bf16  f2b(float x){ return __float2bfloat16(x); }
__device__ __forceinline__ unsigned short f2bits(float x){ return __builtin_bit_cast(unsigned short, f2b(x)); }
__device__ __forceinline__ float bits2f(unsigned short s){ return __builtin_bit_cast(float, ((unsigned)s)<<16); }

// ---------------- prep: CSR of edges grouped by dst ----------------
__global__ void k_csr(const int* __restrict__ ei, int* __restrict__ offs, int* __restrict__ lst)
{
  int tid = threadIdx.x;
  if(tid == 0){
    int cnt[V_], pos[V_];
    for(int v=0;v<V_;v++) cnt[v]=0;
    for(int e=0;e<E_;e++) cnt[ei[2*e+1]]++;
    int off = 0;
    for(int v=0;v<V_;v++){ offs[v]=off; pos[v]=off; off+=cnt[v]; }
    offs[V_] = off;
    for(int e=0;e<E_;e++){ int d = ei[2*e+1]; lst[pos[d]++] = ei[2*e+0]; }
  }
}

// ---------------- prep: weight packing ----------------
__global__ void k_wt(const float* __restrict__ c1W, const float* __restrict__ c2W,
                     const float* __restrict__ s2W, const float* __restrict__ W2,
                     bf16* __restrict__ Wb, float* __restrict__ c2Wt, bf16* __restrict__ WbB)
{
  int i0 = blockIdx.x*blockDim.x + threadIdx.x, stride = gridDim.x*blockDim.x;
  for(int i = i0; i < 307200; i += stride){
    int hlo = i & 15, o = (i>>4)&63, kc = (i>>10)%12, v = i/12288;
    int ks = kc>>2, h = (kc&3)*16 + hlo;
    Wb[i] = f2b(c1W[(o*1600 + v*64 + h)*3 + ks]);
  }
  for(int i = i0; i < 24576; i += stride){
    int o = i & 127, ci = (i>>7)&63, k = i >> 13;
    c2Wt[i] = c2W[(o*64+ci)*3 + k];
  }
  for(int i = i0; i < 8192; i += stride){
    int j = i&7, l=(i>>3)&63, n=(i>>9)&3, kt=i>>11;
    int k = kt*32 + (l>>4)*8 + j;
    int h = n*16 + (l&15);
    float val = (k < 64) ? s2W[k*64 + h] : W2[(k-64)*64 + h];
    WbB[i] = f2b(val);
  }
}

// ---------------- GCN layer 1: block = (16t, b), 512 thr ----------------
__global__ __launch_bounds__(512) void k_gcn1(
    const float* __restrict__ X, const float* __restrict__ s1W, const float* __restrict__ W1,
    const float* __restrict__ s1b, const int* __restrict__ offs, const int* __restrict__ lst,
    bf16* __restrict__ H, float* __restrict__ sum1, float* __restrict__ sq1)
{
  int b = blockIdx.y, t0 = blockIdx.x*16, tid = threadIdx.x;
  __shared__ float Xs[3][16][26], ag[3][16][26];
  __shared__ float sw[3][64], gw[3][64], bias[64];
  __shared__ int so[V_+1], sl[E_];
  __shared__ float red[4][1024];
  if(tid < 192){ sw[tid/64][tid&63] = s1W[tid]; gw[tid/64][tid&63] = W1[tid]; }
  else if(tid < 256) bias[tid-192] = s1b[tid-192];
  else if(tid < 256+V_+1) so[tid-256] = offs[tid-256];
  else if(tid >= 320 && tid < 320+E_) sl[tid-320] = lst[tid-320];
  for(int i=tid; i<1200; i+=512){
    int c = i/400, r = i%400, tl = r/25, v = r%25;
    Xs[c][tl][v] = X[((size_t)(b*3+c)*T_ + t0+tl)*V_ + v];
  }
  __syncthreads();
  for(int i=tid; i<1200; i+=512){
    int c = i/400, r = i%400, tl = r/25, v = r%25;
    float s = 0.f;
    for(int e=so[v]; e<so[v+1]; e++) s += Xs[c][tl][sl[e]];
    ag[c][tl][v] = s;
  }
  __syncthreads();
  int t = tid>>5, l5 = tid&31, h8 = l5&7, vs = l5>>3;
  float swr[3][8], gwr[3][8], br[8];
  #pragma unroll
  for(int c=0;c<3;c++)
    #pragma unroll
    for(int j=0;j<8;j++){ swr[c][j]=sw[c][h8*8+j]; gwr[c][j]=gw[c][h8*8+j]; }
  #pragma unroll
  for(int j=0;j<8;j++) br[j] = bias[h8*8+j];
  float s8[8]={0,0,0,0,0,0,0,0}, q8[8]={0,0,0,0,0,0,0,0};
  bf16* hb = H + ((size_t)b*T_ + t0 + t)*V_*64;
  for(int v=vs; v<V_; v+=4){
    float x0=Xs[0][t][v], x1=Xs[1][t][v], x2=Xs[2][t][v];
    float a0=ag[0][t][v], a1=ag[1][t][v], a2=ag[2][t][v];
    bf16x8 ov;
    #pragma unroll
    for(int j=0;j<8;j++){
      float o = br[j] + x0*swr[0][j] + x1*swr[1][j] + x2*swr[2][j]
                      + a0*gwr[0][j] + a1*gwr[1][j] + a2*gwr[2][j];
      s8[j] += o; q8[j] += o*o;
      ov[j] = (short)f2bits(o);
    }
    *(bf16x8*)&hb[v*64 + h8*8] = ov;
  }
  #pragma unroll
  for(int j=0;j<8;j++) red[vs][t*64 + h8*8 + j] = s8[j];
  __syncthreads();
  for(int i=tid; i<1024; i+=512){
    float s = red[0][i]+red[1][i]+red[2][i]+red[3][i];
    atomicAdd(&sum1[t0*64 + i], s);
  }
  __syncthreads();
  #pragma unroll
  for(int j=0;j<8;j++) red[vs][t*64 + h8*8 + j] = q8[j];
  __syncthreads();
  for(int i=tid; i<1024; i+=512){
    float q = red[0][i]+red[1][i]+red[2][i]+red[3][i];
    atomicAdd(&sq1[t0*64 + i], q);
  }
}

// ---------------- per-(t,h) BN finalize ----------------
__global__ void k_bnfin_th(const float* __restrict__ sum, const float* __restrict__ sq,
                           const float* __restrict__ g, const float* __restrict__ bt,
                           float* __restrict__ scale, float* __restrict__ shift)
{
  int i = blockIdx.x*blockDim.x + threadIdx.x;
  if(i < T_*HD_){
    int h = i & 63;
    float m = sum[i] * (1.0f/1600.0f);
    float v = sq[i] * (1.0f/1600.0f) - m*m;
    float r = rsqrtf(fmaxf(v, 0.f) + 1e-5f);
    float sc = g[h]*r;
    scale[i] = sc;
    shift[i] = bt[h] - m*sc;
  }
}

// ---------------- GCN layer 2 via MFMA 16x16x32, 2 blocks/CU target ----------------
__global__ __launch_bounds__(512,4) void k_gcn2(
    const bf16* Hin, bf16* Hout,   // same pointer
    const float* __restrict__ scale1, const float* __restrict__ shift1,
    const bf16* __restrict__ WbB, const float* __restrict__ s2b,
    const int* __restrict__ offs, const int* __restrict__ lst,
    float* __restrict__ sum2, float* __restrict__ sq2)
{
  int tid = threadIdx.x, lane = tid & 63, wid = tid >> 6;
  int b = blockIdx.y, t0 = blockIdx.x*16;
  __shared__ short Zs[400*72];          // 57.6 KB; reused as red (f32[8][1024] needs 32KB)
  __shared__ short WbBs[8192];          // 16 KB weight B-frags
  __shared__ unsigned int pss[1024];    // 4 KB packed {shift,scale}
  __shared__ int so[V_+1], sl[E_];

  float bias[4];
  #pragma unroll
  for(int n=0;n<4;n++) bias[n] = s2b[n*16 + (lane&15)];
  if(tid < V_+1) so[tid]=offs[tid];
  if(tid >= 64 && tid < 64+E_) sl[tid-64]=lst[tid-64];
  for(int i=tid; i<1024; i+=512){
    pss[i] = ((unsigned)f2bits(shift1[t0*64+i])<<16) | f2bits(scale1[t0*64+i]);
    *(bf16x8*)&WbBs[i*8] = *(const bf16x8*)&WbB[i*8];
  }
  __syncthreads();

  // stage Hn = relu(bn1(H)) into Zs rows (v*16+tl), stride 72
  const bf16* hbase = Hin + ((size_t)b*T_ + t0)*V_*64;
  for(int c=tid; c<3200; c+=512){
    int h8 = c & 7, rr = c >> 3, tl = rr/25, v = rr - tl*25;
    bf16x8 raw = *(const bf16x8*)&hbase[(size_t)rr*64 + h8*8];
    uint4 u0 = *(const uint4*)&pss[tl*64 + h8*8];
    uint4 u1 = *(const uint4*)&pss[tl*64 + h8*8 + 4];
    unsigned int uu[8] = {u0.x,u0.y,u0.z,u0.w,u1.x,u1.y,u1.z,u1.w};
    bf16x8 o;
    #pragma unroll
    for(int j=0;j<8;j++){
      float x = bits2f((unsigned short)raw[j])*bits2f((unsigned short)(uu[j]&0xffffu))
              + bits2f((unsigned short)(uu[j]>>16));
      o[j] = (short)f2bits(fmaxf(x, 0.f));
    }
    *(bf16x8*)&Zs[(v*16 + tl)*72 + h8*8] = o;
  }
  __syncthreads();

  // MFMA with in-register neighbor aggregation
  int l15 = lane & 15, cg = (lane>>4)*8;
  f32x4 accs[4][4] = {};
  #pragma unroll
  for(int vi=0; vi<4; vi++){
    int v = wid + vi*8;
    if(v < V_){
      const short* rowp = &Zs[(v*16 + l15)*72 + cg];
      bf16x8 a0 = *(const bf16x8*)rowp;
      bf16x8 a1 = *(const bf16x8*)(rowp + 32);
      float s0[8]={0,0,0,0,0,0,0,0}, s1[8]={0,0,0,0,0,0,0,0};
      for(int e=so[v]; e<so[v+1]; e++){
        int u = sl[e];
        const short* np = &Zs[(u*16 + l15)*72 + cg];
        bf16x8 n0 = *(const bf16x8*)np;
        bf16x8 n1 = *(const bf16x8*)(np + 32);
        #pragma unroll
        for(int j=0;j<8;j++){ s0[j] += bits2f((unsigned short)n0[j]); s1[j] += bits2f((unsigned short)n1[j]); }
      }
      bf16x8 a2, a3;
      #pragma unroll
      for(int j=0;j<8;j++){ a2[j] = (short)f2bits(s0[j]); a3[j] = (short)f2bits(s1[j]); }
      #pragma unroll
      for(int n=0;n<4;n++){
        bf16x8 b0 = *(const bf16x8*)&WbBs[(( 0+n)*64 + lane)*8];
        accs[vi][n] = __builtin_amdgcn_mfma_f32_16x16x32_bf16(a0, b0, accs[vi][n], 0, 0, 0);
        bf16x8 b1 = *(const bf16x8*)&WbBs[(( 4+n)*64 + lane)*8];
        accs[vi][n] = __builtin_amdgcn_mfma_f32_16x16x32_bf16(a1, b1, accs[vi][n], 0, 0, 0);
        bf16x8 b2 = *(const bf16x8*)&WbBs[(( 8+n)*64 + lane)*8];
        accs[vi][n] = __builtin_amdgcn_mfma_f32_16x16x32_bf16(a2, b2, accs[vi][n], 0, 0, 0);
        bf16x8 b3 = *(const bf16x8*)&WbBs[((12+n)*64 + lane)*8];
        accs[vi][n] = __builtin_amdgcn_mfma_f32_16x16x32_bf16(a3, b3, accs[vi][n], 0, 0, 0);
      }
    }
  }
  __syncthreads();   // all Zs reads done

  // epilogue: bias + stats, transpose via Zs (rr-major rows, stride 72)
  int tlb = (lane>>4)*4;
  f32x4 ssum[4] = {}, ssq[4] = {};
  #pragma unroll
  for(int vi=0; vi<4; vi++){
    int v = wid + vi*8;
    if(v < V_){
      #pragma unroll
      for(int n=0;n<4;n++){
        #pragma unroll
        for(int j=0;j<4;j++){
          float val = accs[vi][n][j] + bias[n];
          ssum[n][j] += val; ssq[n][j] += val*val;
          Zs[((tlb+j)*25 + v)*72 + n*16 + l15] = (short)f2bits(val);
        }
      }
    }
  }
  __syncthreads();

  // cooperative contiguous store
  bf16* hbout = Hout + ((size_t)b*T_ + t0)*V_*64;
  for(int c=tid; c<3200; c+=512){
    bf16x8 o = *(const bf16x8*)&Zs[(c>>3)*72 + (c&7)*8];
    *(bf16x8*)&hbout[(size_t)c*8] = o;
  }
  __syncthreads();

  // stats: two passes through red = Zs (32 KB)
  float* red = (float*)Zs;
  #pragma unroll
  for(int n=0;n<4;n++)
    #pragma unroll
    for(int j=0;j<4;j++)
      red[wid*1024 + (tlb+j)*64 + n*16 + l15] = ssum[n][j];
  __syncthreads();
  for(int i=tid; i<1024; i+=512){
    float s = 0.f;
    #pragma unroll
    for(int w=0;w<8;w++) s += red[w*1024 + i];
    atomicAdd(&sum2[t0*64 + i], s);
  }
  __syncthreads();
  #pragma unroll
  for(int n=0;n<4;n++)
    #pragma unroll
    for(int j=0;j<4;j++)
      red[wid*1024 + (tlb+j)*64 + n*16 + l15] = ssq[n][j];
  __syncthreads();
  for(int i=tid; i<1024; i+=512){
    float q = 0.f;
    #pragma unroll
    for(int w=0;w<8;w++) q += red[w*1024 + i];
    atomicAdd(&sq2[t0*64 + i], q);
  }
}

// ---------------- conv1 via MFMA, K-split over 2 v-groups ----------------
__device__ __forceinline__ bf16x8 loadH8(const bf16* H, int b, int v, int t0, int s){
  int ti = s>>3, h0 = (s&7)*8, t = t0-1+ti;
  bf16x8 r = {0,0,0,0,0,0,0,0};
  if(t >= 0 && t < T_) r = *(const bf16x8*)&H[(((size_t)b*T_+t)*V_ + v)*HD_ + h0];
  return r;
}

__device__ __forceinline__ void xform_store(short* zbuf, const unsigned int* sshf, int s, bf16x8 raw){
  int ti = s>>3, h0 = (s&7)*8;
  uint4 u0 = *(const uint4*)&sshf[ti*64 + h0];
  uint4 u1 = *(const uint4*)&sshf[ti*64 + h0 + 4];
  unsigned int uu[8] = {u0.x,u0.y,u0.z,u0.w,u1.x,u1.y,u1.z,u1.w};
  bf16x8 outv;
  #pragma unroll
  for(int j=0;j<8;j++){
    float scl = bits2f((unsigned short)(uu[j] & 0xffffu));
    float shf = bits2f((unsigned short)(uu[j] >> 16));
    float x = bits2f((unsigned short)raw[j]);
    outv[j] = (short)f2bits(fmaxf(x*scl + shf, 0.f));
  }
  *(bf16x8*)&zbuf[ti*72 + h0] = outv;
}

__global__ __launch_bounds__(256,4) void k_conv1(
    const bf16* __restrict__ H, const float* __restrict__ scale2, const float* __restrict__ shift2,
    const bf16* __restrict__ Wb, float* __restrict__ P)
{
  int b = blockIdx.y, t0 = blockIdx.x*64, vg = blockIdx.z, tid = threadIdx.x;
  int lane = tid & 63, w = tid >> 6;
  int v0 = vg ? 13 : 0, nv = vg ? 12 : 13;
  __shared__ unsigned int sshf[66*64];
  __shared__ short zs[2][66*72];

  for(int i = tid; i < 66*64; i += 256){
    int ti = i>>6, h = i&63, t = t0-1+ti;
    unsigned int u = 0;
    if(t >= 0 && t < T_){
      u = ((unsigned)f2bits(shift2[t*64+h])<<16) | f2bits(scale2[t*64+h]);
    }
    sshf[i] = u;
  }
  __syncthreads();

  {
    bf16x8 a0 = loadH8(H,b,v0,t0,tid);
    bf16x8 a1 = loadH8(H,b,v0,t0,tid+256);
    bf16x8 a2 = {0,0,0,0,0,0,0,0};
    if(tid<16) a2 = loadH8(H,b,v0,t0,tid+512);
    xform_store(zs[0], sshf, tid, a0);
    xform_store(zs[0], sshf, tid+256, a1);
    if(tid<16) xform_store(zs[0], sshf, tid+512, a2);
  }
  __syncthreads();

  int ow = w & 1, twv = (w>>1)*32;
  int o0 = ow*32;
  f32x16 acc = {};
  for(int i=0; i<nv; i++){
    int v = v0 + i, cur = i & 1;
    bf16x8 a0={0,0,0,0,0,0,0,0}, a1={0,0,0,0,0,0,0,0}, a2={0,0,0,0,0,0,0,0};
    if(i+1 < nv){
      a0 = loadH8(H,b,v+1,t0,tid);
      a1 = loadH8(H,b,v+1,t0,tid+256);
      if(tid<16) a2 = loadH8(H,b,v+1,t0,tid+512);
    }
    const short* zbuf = zs[cur];
    #pragma unroll
    for(int kc=0; kc<12; kc++){
      int ks = kc>>2;
      bf16x8 af = *(const bf16x8*)&Wb[((v*12+kc)*64 + o0 + (lane&31))*16 + (lane>>5)*8];
      int row = twv + (lane&31) + ks;
      int col = (kc&3)*16 + (lane>>5)*8;
      bf16x8 bfr = *(const bf16x8*)&zbuf[row*72 + col];
      acc = __builtin_amdgcn_mfma_f32_32x32x16_bf16(af, bfr, acc, 0, 0, 0);
    }
    if(i+1 < nv){
      short* znext = zs[cur^1];
      xform_store(znext, sshf, tid, a0);
      xform_store(znext, sshf, tid+256, a1);
      if(tid<16) xform_store(znext, sshf, tid+512, a2);
    }
    __syncthreads();
  }
  int t = t0 + twv + (lane&31);
  size_t pbase = ((size_t)vg*B_ + b)*64;
  #pragma unroll
  for(int r=0;r<16;r++){
    int o = o0 + (r&3) + 8*(r>>2) + 4*(lane>>5);
    P[(pbase + o)*T_ + t] = acc[r];
  }
}

// ---------------- reduce partial planes -> C1 (+bias) and BN3 stats ----------------
__global__ __launch_bounds__(128) void k_red1(
    const float* __restrict__ P, const float* __restrict__ c1b,
    float* __restrict__ C1, float* __restrict__ sum3, float* __restrict__ sq3)
{
  int o = blockIdx.x, b = blockIdx.y, tid = threadIdx.x;
  size_t base = ((size_t)b*64 + o)*T_ + tid*4;
  float4 x = *(const float4*)&P[base];
  float4 y = *(const float4*)&P[2097152 + base];
  float bias = c1b[o];
  float4 r;
  r.x = x.x + y.x + bias; r.y = x.y + y.y + bias;
  r.z = x.z + y.z + bias; r.w = x.w + y.w + bias;
  *(float4*)&C1[base] = r;
  float s = r.x + r.y + r.z + r.w;
  float q = r.x*r.x + r.y*r.y + r.z*r.z + r.w*r.w;
  for(int off=32; off; off>>=1){ s += __shfl_down(s, off); q += __shfl_down(q, off); }
  __shared__ float rs[2], rq[2];
  if((tid&63)==0){ rs[tid>>6]=s; rq[tid>>6]=q; }
  __syncthreads();
  if(tid==0){ atomicAdd(&sum3[o], rs[0]+rs[1]); atomicAdd(&sq3[o], rq[0]+rq[1]); }
}

// ---------------- per-channel BN finalize ----------------
__global__ void k_bnfin_ch(const float* __restrict__ sum, const float* __restrict__ sq,
                           const float* __restrict__ g, const float* __restrict__ bt,
                           float* __restrict__ scale, float* __restrict__ shift,
                           int nch, float inv_count)
{
  int i = blockIdx.x*blockDim.x + threadIdx.x;
  if(i < nch){
    float m = sum[i]*inv_count;
    float v = sq[i]*inv_count - m*m;
    float r = rsqrtf(fmaxf(v, 0.f) + 1e-5f);
    float sc = g[i]*r;
    scale[i]=sc; shift[i]=bt[i]-m*sc;
  }
}

// ---------------- conv2 ----------------
__global__ __launch_bounds__(256) void k_conv2(
    const float* __restrict__ C1, const float* __restrict__ scale3, const float* __restrict__ shift3,
    const float* __restrict__ c2Wt, const float* __restrict__ c2b,
    float* __restrict__ C2, float* __restrict__ sum4, float* __restrict__ sq4)
{
  int b = blockIdx.y, t0 = blockIdx.x*64, tid = threadIdx.x;
  __shared__ float z[64][69];
  __shared__ float scl[64], shf[64];
  __shared__ float ps[128][9], pq[128][9];
  if(tid < 64){ scl[tid]=scale3[tid]; shf[tid]=shift3[tid]; }
  __syncthreads();
  for(int i=tid; i<64*68; i+=256){
    int ti = i % 68, ci = i / 68;
    int t = t0 - 2 + ti;
    float val = 0.f;
    if(t >= 0 && t < T_){
      val = fmaxf(C1[((size_t)b*64+ci)*T_ + t]*scl[ci] + shf[ci], 0.f);
    }
    z[ci][ti] = val;
  }
  __syncthreads();
  int og = tid & 31, tg = tid >> 5;
  int o0 = og*4;
  float acc[8][4];
  #pragma unroll
  for(int i=0;i<8;i++){
    #pragma unroll
    for(int j=0;j<4;j++) acc[i][j]=0.f;
  }
  for(int ci=0; ci<64; ci++){
    float4 w0 = *(const float4*)&c2Wt[0*8192 + ci*128 + o0];
    float4 w1 = *(const float4*)&c2Wt[1*8192 + ci*128 + o0];
    float4 w2 = *(const float4*)&c2Wt[2*8192 + ci*128 + o0];
    float zr[12];
    #pragma unroll
    for(int j=0;j<12;j++) zr[j] = z[ci][tg*8 + j];
    #pragma unroll
    for(int tt=0;tt<8;tt++){
      float z0=zr[tt], z1=zr[tt+2], z2=zr[tt+4];
      acc[tt][0] += w0.x*z0 + w1.x*z1 + w2.x*z2;
      acc[tt][1] += w0.y*z0 + w1.y*z1 + w2.y*z2;
      acc[tt][2] += w0.z*z0 + w1.z*z1 + w2.z*z2;
      acc[tt][3] += w0.w*z0 + w1.w*z1 + w2.w*z2;
    }
  }
  #pragma unroll
  for(int oo=0;oo<4;oo++){
    float bsv = c2b[o0+oo];
    float s=0.f, q=0.f;
    #pragma unroll
    for(int tt=0;tt<8;tt++){
      float y = acc[tt][oo] + bsv;
      C2[((size_t)b*128 + o0+oo)*T_ + t0 + tg*8 + tt] = y;
      s += y; q += y*y;
    }
    ps[o0+oo][tg]=s; pq[o0+oo][tg]=q;
  }
  __syncthreads();
  if(tid < 128){
    float s=0.f, q=0.f;
    for(int g=0; g<8; g++){ s+=ps[tid][g]; q+=pq[tid][g]; }
    atomicAdd(&sum4[tid], s); atomicAdd(&sq4[tid], q);
  }
}

// ---------------- head ----------------
__global__ __launch_bounds__(256) void k_head(
    const float* __restrict__ C2, const float* __restrict__ scale4, const float* __restrict__ shift4,
    const float* __restrict__ fcW, const float* __restrict__ fcb, float* __restrict__ out)
{
  int b = blockIdx.x, tid = threadIdx.x;
  __shared__ float mean[128];
  __shared__ float ms[256];
  int ch = tid >> 1, p = tid & 1;
  float scl = scale4[ch], shf = shift4[ch];
  const float* src = C2 + ((size_t)b*128 + ch)*T_ + p*256;
  float s = 0.f;
  for(int i=0;i<256;i++){
    s += fmaxf(src[i]*scl + shf, 0.f);
  }
  ms[tid] = s;
  __syncthreads();
  if(tid < 128) mean[tid] = (ms[2*tid] + ms[2*tid+1]) * (1.0f/512.0f);
  __syncthreads();
  if(tid < NC_){
    float acc = fcb[tid];
    for(int c=0;c<128;c++) acc += mean[c]*fcW[c*NC_ + tid];
    out[b*NC_ + tid] = acc;
  }
}

// ---------------- launch ----------------
extern "C" void kernel_launch(void* const* d_in, const int* in_sizes, int n_in,
                              void* d_out, int out_size, void* d_ws, size_t ws_size,
                              hipStream_t stream)
{
  const float* X   = (const float*)d_in[0];
  const int*   ei  = (const int*)  d_in[1];
  const float* W1  = (const float*)d_in[2];
  const float* s1W = (const float*)d_in[3];
  const float* s1b = (const float*)d_in[4];
  const float* g1  = (const float*)d_in[5];
  const float* b1  = (const float*)d_in[6];
  const float* W2  = (const float*)d_in[7];
  const float* s2W = (const float*)d_in[8];
  const float* s2b = (const float*)d_in[9];
  const float* g2  = (const float*)d_in[10];
  const float* b2  = (const float*)d_in[11];
  const float* c1W = (const float*)d_in[12];
  const float* c1b = (const float*)d_in[13];
  const float* tg1 = (const float*)d_in[14];
  const float* tb1 = (const float*)d_in[15];
  const float* c2W = (const float*)d_in[16];
  const float* c2b = (const float*)d_in[17];
  const float* tg2 = (const float*)d_in[18];
  const float* tb2 = (const float*)d_in[19];
  const float* fcW = (const float*)d_in[20];
  const float* fcb = (const float*)d_in[21];

  char* ws = (char*)d_ws;
  bf16*  H     = (bf16*) (ws);                       // 104,857,600 B
  float* C1    = (float*)(ws + 104857600);           // 8 MB
  float* C2    = (float*)(ws + 113246208);           // 16 MB (also conv1 partial planes)
  float* P     = C2;
  bf16*  Wb    = (bf16*) (ws + 130023424);
  float* c2Wt  = (float*)(ws + 131252224);
  bf16*  WbB   = (bf16*) (ws + 131350528);
  float* stats = (float*)(ws + 131366912);
  float* sum1 = stats;            float* sq1 = stats + 32768;
  float* sum2 = stats + 65536;    float* sq2 = stats + 98304;
  float* sum3 = stats + 131072;   float* sq3 = sum3 + 64;
  float* sum4 = sq3 + 64;         float* sq4 = sum4 + 128;
  float* scale1 = stats + 131456; float* shift1 = scale1 + 32768;
  float* scale2 = shift1 + 32768; float* shift2 = scale2 + 32768;
  float* scale3 = shift2 + 32768; float* shift3 = scale3 + 64;
  float* scale4 = shift3 + 64;    float* shift4 = scale4 + 128;
  int* csr_off = (int*)(shift4 + 128);
  int* csr_lst = csr_off + 32;

  hipMemsetAsync(stats, 0, (size_t)131456*sizeof(float), stream);
  k_csr<<<1, 64, 0, stream>>>(ei, csr_off, csr_lst);
  k_wt<<<256, 256, 0, stream>>>(c1W, c2W, s2W, W2, Wb, c2Wt, WbB);

  k_gcn1<<<dim3(T_/16, B_), 512, 0, stream>>>(X, s1W, W1, s1b, csr_off, csr_lst, H, sum1, sq1);
  k_bnfin_th<<<128, 256, 0, stream>>>(sum1, sq1, g1, b1, scale1, shift1);
  k_gcn2<<<dim3(T_/16, B_), 512, 0, stream>>>(H, H, scale1, shift1, WbB, s2b, csr_off, csr_lst, sum2, sq2);
  k_bnfin_th<<<128, 256, 0, stream>>>(sum2, sq2, g2, b2, scale2, shift2);
  k_conv1<<<dim3(8, B_, 2), 256, 0, stream>>>(H, scale2, shift2, Wb, P);
  k_red1<<<dim3(64, B_), 128, 0, stream>>>(P, c1b, C1, sum3, sq3);
  k_bnfin_ch<<<1, 64, 0, stream>>>(sum3, sq3, tg1, tb1, scale3, shift3, 64, 1.0f/32768.0f);
  k_conv2<<<dim3(8, B_), 256, 0, stream>>>(C1, scale3, shift3, c2Wt, c2b, C2, sum4, sq4);
  k_bnfin_ch<<<1, 128, 0, stream>>>(sum4, sq4, tg2, tb2, scale4, shift4, 128, 1.0f/32768.0f);
  k_head<<<B_, 256, 0, stream>>>(C2, scale4, shift4, fcW, fcb, (float*)d_out);
}

// Round 6
// 279.105 us; speedup vs baseline: 4.3571x; 1.0724x over previous
//
#include <hip/hip_runtime.h>
#include <hip/hip_bf16.h>
#include <cstddef>

using bf16 = __hip_bfloat16;
typedef __attribute__((ext_vector_type(8)))  short bf16x8;
typedef __attribute__((ext_vector_type(4)))  float f32x4;
typedef __attribute__((ext_vector_type(16))) float f32x16;

#define B_   64
#define T_   512
#define V_   25
#define HD_  64
#define E_   48
#define NC_  60

__device__ __forceinline__ float b2f(bf16 x){ return __bfloat162float(x); }
__device__ __forceinline__ bf16  f2b(float x){ return __float2bfloat16(x); }
__device__ __forceinline__ unsigned short f2bits(float x){ return __builtin_bit_cast(unsigned short, f2b(x)); }
__device__ __forceinline__ float bits2f(unsigned short s){ return __builtin_bit_cast(float, ((unsigned)s)<<16); }

// ---------------- prep: CSR of edges grouped by dst ----------------
__global__ void k_csr(const int* __restrict__ ei, int* __restrict__ offs, int* __restrict__ lst)
{
  int tid = threadIdx.x;
  if(tid == 0){
    int cnt[V_], pos[V_];
    for(int v=0;v<V_;v++) cnt[v]=0;
    for(int e=0;e<E_;e++) cnt[ei[2*e+1]]++;
    int off = 0;
    for(int v=0;v<V_;v++){ offs[v]=off; pos[v]=off; off+=cnt[v]; }
    offs[V_] = off;
    for(int e=0;e<E_;e++){ int d = ei[2*e+1]; lst[pos[d]++] = ei[2*e+0]; }
  }
}

// ---------------- prep: weight packing ----------------
__global__ void k_wt(const float* __restrict__ c1W, const float* __restrict__ c2W,
                     const float* __restrict__ s2W, const float* __restrict__ W2,
                     bf16* __restrict__ Wb, bf16* __restrict__ Wb2, bf16* __restrict__ WbB)
{
  int i0 = blockIdx.x*blockDim.x + threadIdx.x, stride = gridDim.x*blockDim.x;
  for(int i = i0; i < 307200; i += stride){
    int hlo = i & 15, o = (i>>4)&63, kc = (i>>10)%12, v = i/12288;
    int ks = kc>>2, h = (kc&3)*16 + hlo;
    Wb[i] = f2b(c1W[(o*1600 + v*64 + h)*3 + ks]);
  }
  for(int i = i0; i < 24576; i += stride){
    int hlo = i & 15, o = (i>>4)&127, kc = i>>11;    // kc in 0..11, ks-major
    int ks = kc>>2, c = (kc&3)*16 + hlo;
    Wb2[i] = f2b(c2W[(o*64 + c)*3 + ks]);
  }
  for(int i = i0; i < 8192; i += stride){
    int j = i&7, l=(i>>3)&63, n=(i>>9)&3, kt=i>>11;
    int k = kt*32 + (l>>4)*8 + j;
    int h = n*16 + (l&15);
    float val = (k < 64) ? s2W[k*64 + h] : W2[(k-64)*64 + h];
    WbB[i] = f2b(val);
  }
}

// ---------------- GCN layer 1: block = (16t, b), 512 thr; partial stats ----------------
__global__ __launch_bounds__(512) void k_gcn1(
    const float* __restrict__ X, const float* __restrict__ s1W, const float* __restrict__ W1,
    const float* __restrict__ s1b, const int* __restrict__ offs, const int* __restrict__ lst,
    bf16* __restrict__ H, float* __restrict__ part)
{
  int b = blockIdx.y, t0 = blockIdx.x*16, tid = threadIdx.x;
  __shared__ float Xs[3][16][26], ag[3][16][26];
  __shared__ float sw[3][64], gw[3][64], bias[64];
  __shared__ int so[V_+1], sl[E_];
  __shared__ float red[4][1024];
  if(tid < 192){ sw[tid/64][tid&63] = s1W[tid]; gw[tid/64][tid&63] = W1[tid]; }
  else if(tid < 256) bias[tid-192] = s1b[tid-192];
  else if(tid < 256+V_+1) so[tid-256] = offs[tid-256];
  else if(tid >= 320 && tid < 320+E_) sl[tid-320] = lst[tid-320];
  for(int i=tid; i<1200; i+=512){
    int c = i/400, r = i%400, tl = r/25, v = r%25;
    Xs[c][tl][v] = X[((size_t)(b*3+c)*T_ + t0+tl)*V_ + v];
  }
  __syncthreads();
  for(int i=tid; i<1200; i+=512){
    int c = i/400, r = i%400, tl = r/25, v = r%25;
    float s = 0.f;
    for(int e=so[v]; e<so[v+1]; e++) s += Xs[c][tl][sl[e]];
    ag[c][tl][v] = s;
  }
  __syncthreads();
  int t = tid>>5, l5 = tid&31, h8 = l5&7, vs = l5>>3;
  float swr[3][8], gwr[3][8], br[8];
  #pragma unroll
  for(int c=0;c<3;c++)
    #pragma unroll
    for(int j=0;j<8;j++){ swr[c][j]=sw[c][h8*8+j]; gwr[c][j]=gw[c][h8*8+j]; }
  #pragma unroll
  for(int j=0;j<8;j++) br[j] = bias[h8*8+j];
  float s8[8]={0,0,0,0,0,0,0,0}, q8[8]={0,0,0,0,0,0,0,0};
  bf16* hb = H + ((size_t)b*T_ + t0 + t)*V_*64;
  for(int v=vs; v<V_; v+=4){
    float x0=Xs[0][t][v], x1=Xs[1][t][v], x2=Xs[2][t][v];
    float a0=ag[0][t][v], a1=ag[1][t][v], a2=ag[2][t][v];
    bf16x8 ov;
    #pragma unroll
    for(int j=0;j<8;j++){
      float o = br[j] + x0*swr[0][j] + x1*swr[1][j] + x2*swr[2][j]
                      + a0*gwr[0][j] + a1*gwr[1][j] + a2*gwr[2][j];
      s8[j] += o; q8[j] += o*o;
      ov[j] = (short)f2bits(o);
    }
    *(bf16x8*)&hb[v*64 + h8*8] = ov;
  }
  size_t pb = ((size_t)blockIdx.x*64 + blockIdx.y)*2048;
  #pragma unroll
  for(int j=0;j<8;j++) red[vs][t*64 + h8*8 + j] = s8[j];
  __syncthreads();
  for(int i=tid; i<1024; i+=512)
    part[pb + i] = red[0][i]+red[1][i]+red[2][i]+red[3][i];
  __syncthreads();
  #pragma unroll
  for(int j=0;j<8;j++) red[vs][t*64 + h8*8 + j] = q8[j];
  __syncthreads();
  for(int i=tid; i<1024; i+=512)
    part[pb + 1024 + i] = red[0][i]+red[1][i]+red[2][i]+red[3][i];
}

// ---------------- per-(t,h) BN finalize from block partials ----------------
__global__ void k_bnfin_th(const float* __restrict__ part,
                           const float* __restrict__ g, const float* __restrict__ bt,
                           float* __restrict__ scale, float* __restrict__ shift)
{
  int i = blockIdx.x*blockDim.x + threadIdx.x;
  if(i < T_*HD_){
    int h = i & 63, t = i >> 6, bx = t >> 4, tl = t & 15;
    const float* p = part + ((size_t)bx*64)*2048 + tl*64 + h;
    float s = 0.f, q = 0.f;
    for(int b=0;b<64;b++){ s += p[(size_t)b*2048]; q += p[(size_t)b*2048 + 1024]; }
    float m = s * (1.0f/1600.0f);
    float v = q * (1.0f/1600.0f) - m*m;
    float r = rsqrtf(fmaxf(v, 0.f) + 1e-5f);
    float sc = g[h]*r;
    scale[i] = sc;
    shift[i] = bt[h] - m*sc;
  }
}

// ---------------- GCN layer 2 via MFMA 16x16x32; partial stats ----------------
__global__ __launch_bounds__(512,4) void k_gcn2(
    const bf16* Hin, bf16* Hout,   // same pointer
    const float* __restrict__ scale1, const float* __restrict__ shift1,
    const bf16* __restrict__ WbB, const float* __restrict__ s2b,
    const int* __restrict__ offs, const int* __restrict__ lst,
    float* __restrict__ part)
{
  int tid = threadIdx.x, lane = tid & 63, wid = tid >> 6;
  int b = blockIdx.y, t0 = blockIdx.x*16;
  __shared__ short Zs[400*72];          // 57.6 KB; reused as red f32[8][1024]
  __shared__ short WbBs[8192];          // 16 KB weight B-frags
  __shared__ unsigned int pss[1024];    // 4 KB packed {shift,scale}
  __shared__ int so[V_+1], sl[E_];

  float bias[4];
  #pragma unroll
  for(int n=0;n<4;n++) bias[n] = s2b[n*16 + (lane&15)];
  if(tid < V_+1) so[tid]=offs[tid];
  if(tid >= 64 && tid < 64+E_) sl[tid-64]=lst[tid-64];
  for(int i=tid; i<1024; i+=512){
    pss[i] = ((unsigned)f2bits(shift1[t0*64+i])<<16) | f2bits(scale1[t0*64+i]);
    *(bf16x8*)&WbBs[i*8] = *(const bf16x8*)&WbB[i*8];
  }
  __syncthreads();

  // stage Hn = relu(bn1(H)) into Zs rows (v*16+tl), stride 72
  const bf16* hbase = Hin + ((size_t)b*T_ + t0)*V_*64;
  for(int c=tid; c<3200; c+=512){
    int h8 = c & 7, rr = c >> 3, tl = rr/25, v = rr - tl*25;
    bf16x8 raw = *(const bf16x8*)&hbase[(size_t)rr*64 + h8*8];
    uint4 u0 = *(const uint4*)&pss[tl*64 + h8*8];
    uint4 u1 = *(const uint4*)&pss[tl*64 + h8*8 + 4];
    unsigned int uu[8] = {u0.x,u0.y,u0.z,u0.w,u1.x,u1.y,u1.z,u1.w};
    bf16x8 o;
    #pragma unroll
    for(int j=0;j<8;j++){
      float x = bits2f((unsigned short)raw[j])*bits2f((unsigned short)(uu[j]&0xffffu))
              + bits2f((unsigned short)(uu[j]>>16));
      o[j] = (short)f2bits(fmaxf(x, 0.f));
    }
    *(bf16x8*)&Zs[(v*16 + tl)*72 + h8*8] = o;
  }
  __syncthreads();

  // MFMA with in-register neighbor aggregation
  int l15 = lane & 15, cg = (lane>>4)*8;
  f32x4 accs[4][4] = {};
  #pragma unroll
  for(int vi=0; vi<4; vi++){
    int v = wid + vi*8;
    if(v < V_){
      const short* rowp = &Zs[(v*16 + l15)*72 + cg];
      bf16x8 a0 = *(const bf16x8*)rowp;
      bf16x8 a1 = *(const bf16x8*)(rowp + 32);
      float s0[8]={0,0,0,0,0,0,0,0}, s1[8]={0,0,0,0,0,0,0,0};
      for(int e=so[v]; e<so[v+1]; e++){
        int u = sl[e];
        const short* np = &Zs[(u*16 + l15)*72 + cg];
        bf16x8 n0 = *(const bf16x8*)np;
        bf16x8 n1 = *(const bf16x8*)(np + 32);
        #pragma unroll
        for(int j=0;j<8;j++){ s0[j] += bits2f((unsigned short)n0[j]); s1[j] += bits2f((unsigned short)n1[j]); }
      }
      bf16x8 a2, a3;
      #pragma unroll
      for(int j=0;j<8;j++){ a2[j] = (short)f2bits(s0[j]); a3[j] = (short)f2bits(s1[j]); }
      #pragma unroll
      for(int n=0;n<4;n++){
        bf16x8 b0 = *(const bf16x8*)&WbBs[(( 0+n)*64 + lane)*8];
        accs[vi][n] = __builtin_amdgcn_mfma_f32_16x16x32_bf16(a0, b0, accs[vi][n], 0, 0, 0);
        bf16x8 b1 = *(const bf16x8*)&WbBs[(( 4+n)*64 + lane)*8];
        accs[vi][n] = __builtin_amdgcn_mfma_f32_16x16x32_bf16(a1, b1, accs[vi][n], 0, 0, 0);
        bf16x8 b2 = *(const bf16x8*)&WbBs[(( 8+n)*64 + lane)*8];
        accs[vi][n] = __builtin_amdgcn_mfma_f32_16x16x32_bf16(a2, b2, accs[vi][n], 0, 0, 0);
        bf16x8 b3 = *(const bf16x8*)&WbBs[((12+n)*64 + lane)*8];
        accs[vi][n] = __builtin_amdgcn_mfma_f32_16x16x32_bf16(a3, b3, accs[vi][n], 0, 0, 0);
      }
    }
  }
  __syncthreads();   // all Zs reads done

  // epilogue: bias + stats, transpose via Zs (rr-major rows, stride 72)
  int tlb = (lane>>4)*4;
  f32x4 ssum[4] = {}, ssq[4] = {};
  #pragma unroll
  for(int vi=0; vi<4; vi++){
    int v = wid + vi*8;
    if(v < V_){
      #pragma unroll
      for(int n=0;n<4;n++){
        #pragma unroll
        for(int j=0;j<4;j++){
          float val = accs[vi][n][j] + bias[n];
          ssum[n][j] += val; ssq[n][j] += val*val;
          Zs[((tlb+j)*25 + v)*72 + n*16 + l15] = (short)f2bits(val);
        }
      }
    }
  }
  __syncthreads();

  // cooperative contiguous store
  bf16* hbout = Hout + ((size_t)b*T_ + t0)*V_*64;
  for(int c=tid; c<3200; c+=512){
    bf16x8 o = *(const bf16x8*)&Zs[(c>>3)*72 + (c&7)*8];
    *(bf16x8*)&hbout[(size_t)c*8] = o;
  }
  __syncthreads();

  // stats: two passes through red = Zs; write block partials (no atomics)
  float* red = (float*)Zs;
  size_t pb = ((size_t)blockIdx.x*64 + blockIdx.y)*2048;
  #pragma unroll
  for(int n=0;n<4;n++)
    #pragma unroll
    for(int j=0;j<4;j++)
      red[wid*1024 + (tlb+j)*64 + n*16 + l15] = ssum[n][j];
  __syncthreads();
  for(int i=tid; i<1024; i+=512){
    float s = 0.f;
    #pragma unroll
    for(int w=0;w<8;w++) s += red[w*1024 + i];
    part[pb + i] = s;
  }
  __syncthreads();
  #pragma unroll
  for(int n=0;n<4;n++)
    #pragma unroll
    for(int j=0;j<4;j++)
      red[wid*1024 + (tlb+j)*64 + n*16 + l15] = ssq[n][j];
  __syncthreads();
  for(int i=tid; i<1024; i+=512){
    float q = 0.f;
    #pragma unroll
    for(int w=0;w<8;w++) q += red[w*1024 + i];
    part[pb + 1024 + i] = q;
  }
}

// ---------------- conv1 via MFMA, K-split over 2 v-groups ----------------
__device__ __forceinline__ bf16x8 loadH8(const bf16* H, int b, int v, int t0, int s){
  int ti = s>>3, h0 = (s&7)*8, t = t0-1+ti;
  bf16x8 r = {0,0,0,0,0,0,0,0};
  if(t >= 0 && t < T_) r = *(const bf16x8*)&H[(((size_t)b*T_+t)*V_ + v)*HD_ + h0];
  return r;
}

__device__ __forceinline__ void xform_store(short* zbuf, const unsigned int* sshf, int s, bf16x8 raw){
  int ti = s>>3, h0 = (s&7)*8;
  uint4 u0 = *(const uint4*)&sshf[ti*64 + h0];
  uint4 u1 = *(const uint4*)&sshf[ti*64 + h0 + 4];
  unsigned int uu[8] = {u0.x,u0.y,u0.z,u0.w,u1.x,u1.y,u1.z,u1.w};
  bf16x8 outv;
  #pragma unroll
  for(int j=0;j<8;j++){
    float scl = bits2f((unsigned short)(uu[j] & 0xffffu));
    float shf = bits2f((unsigned short)(uu[j] >> 16));
    float x = bits2f((unsigned short)raw[j]);
    outv[j] = (short)f2bits(fmaxf(x*scl + shf, 0.f));
  }
  *(bf16x8*)&zbuf[ti*72 + h0] = outv;
}

__global__ __launch_bounds__(256,4) void k_conv1(
    const bf16* __restrict__ H, const float* __restrict__ scale2, const float* __restrict__ shift2,
    const bf16* __restrict__ Wb, float* __restrict__ P)
{
  int b = blockIdx.y, t0 = blockIdx.x*64, vg = blockIdx.z, tid = threadIdx.x;
  int lane = tid & 63, w = tid >> 6;
  int v0 = vg ? 13 : 0, nv = vg ? 12 : 13;
  __shared__ unsigned int sshf[66*64];
  __shared__ short zs[2][66*72];

  for(int i = tid; i < 66*64; i += 256){
    int ti = i>>6, h = i&63, t = t0-1+ti;
    unsigned int u = 0;
    if(t >= 0 && t < T_){
      u = ((unsigned)f2bits(shift2[t*64+h])<<16) | f2bits(scale2[t*64+h]);
    }
    sshf[i] = u;
  }
  __syncthreads();

  {
    bf16x8 a0 = loadH8(H,b,v0,t0,tid);
    bf16x8 a1 = loadH8(H,b,v0,t0,tid+256);
    bf16x8 a2 = {0,0,0,0,0,0,0,0};
    if(tid<16) a2 = loadH8(H,b,v0,t0,tid+512);
    xform_store(zs[0], sshf, tid, a0);
    xform_store(zs[0], sshf, tid+256, a1);
    if(tid<16) xform_store(zs[0], sshf, tid+512, a2);
  }
  __syncthreads();

  int ow = w & 1, twv = (w>>1)*32;
  int o0 = ow*32;
  f32x16 acc = {};
  for(int i=0; i<nv; i++){
    int v = v0 + i, cur = i & 1;
    bf16x8 a0={0,0,0,0,0,0,0,0}, a1={0,0,0,0,0,0,0,0}, a2={0,0,0,0,0,0,0,0};
    if(i+1 < nv){
      a0 = loadH8(H,b,v+1,t0,tid);
      a1 = loadH8(H,b,v+1,t0,tid+256);
      if(tid<16) a2 = loadH8(H,b,v+1,t0,tid+512);
    }
    const short* zbuf = zs[cur];
    #pragma unroll
    for(int kc=0; kc<12; kc++){
      int ks = kc>>2;
      bf16x8 af = *(const bf16x8*)&Wb[((v*12+kc)*64 + o0 + (lane&31))*16 + (lane>>5)*8];
      int row = twv + (lane&31) + ks;
      int col = (kc&3)*16 + (lane>>5)*8;
      bf16x8 bfr = *(const bf16x8*)&zbuf[row*72 + col];
      acc = __builtin_amdgcn_mfma_f32_32x32x16_bf16(af, bfr, acc, 0, 0, 0);
    }
    if(i+1 < nv){
      short* znext = zs[cur^1];
      xform_store(znext, sshf, tid, a0);
      xform_store(znext, sshf, tid+256, a1);
      if(tid<16) xform_store(znext, sshf, tid+512, a2);
    }
    __syncthreads();
  }
  int t = t0 + twv + (lane&31);
  size_t pbase = ((size_t)vg*B_ + b)*64;
  #pragma unroll
  for(int r=0;r<16;r++){
    int o = o0 + (r&3) + 8*(r>>2) + 4*(lane>>5);
    P[(pbase + o)*T_ + t] = acc[r];
  }
}

// ---------------- reduce partial planes -> C1 (+bias) and BN3 stats ----------------
__global__ __launch_bounds__(128) void k_red1(
    const float* __restrict__ P, const float* __restrict__ c1b,
    float* __restrict__ C1, float* __restrict__ sum3, float* __restrict__ sq3)
{
  int o = blockIdx.x, b = blockIdx.y, tid = threadIdx.x;
  size_t base = ((size_t)b*64 + o)*T_ + tid*4;
  float4 x = *(const float4*)&P[base];
  float4 y = *(const float4*)&P[2097152 + base];
  float bias = c1b[o];
  float4 r;
  r.x = x.x + y.x + bias; r.y = x.y + y.y + bias;
  r.z = x.z + y.z + bias; r.w = x.w + y.w + bias;
  *(float4*)&C1[base] = r;
  float s = r.x + r.y + r.z + r.w;
  float q = r.x*r.x + r.y*r.y + r.z*r.z + r.w*r.w;
  for(int off=32; off; off>>=1){ s += __shfl_down(s, off); q += __shfl_down(q, off); }
  __shared__ float rs[2], rq[2];
  if((tid&63)==0){ rs[tid>>6]=s; rq[tid>>6]=q; }
  __syncthreads();
  if(tid==0){ atomicAdd(&sum3[o], rs[0]+rs[1]); atomicAdd(&sq3[o], rq[0]+rq[1]); }
}

// ---------------- per-channel BN finalize ----------------
__global__ void k_bnfin_ch(const float* __restrict__ sum, const float* __restrict__ sq,
                           const float* __restrict__ g, const float* __restrict__ bt,
                           float* __restrict__ scale, float* __restrict__ shift,
                           int nch, float inv_count)
{
  int i = blockIdx.x*blockDim.x + threadIdx.x;
  if(i < nch){
    float m = sum[i]*inv_count;
    float v = sq[i]*inv_count - m*m;
    float r = rsqrtf(fmaxf(v, 0.f) + 1e-5f);
    float sc = g[i]*r;
    scale[i]=sc; shift[i]=bt[i]-m*sc;
  }
}

// ---------------- conv2 via MFMA 32x32x16 (K = 192 = ks-major x 64c) ----------------
__global__ __launch_bounds__(256) void k_conv2(
    const float* __restrict__ C1, const float* __restrict__ scale3, const float* __restrict__ shift3,
    const bf16* __restrict__ Wb2, const float* __restrict__ c2b,
    float* __restrict__ C2)
{
  int b = blockIdx.y, t0 = blockIdx.x*64, tid = threadIdx.x;
  int lane = tid & 63, w = tid >> 6;
  __shared__ short zT[68*72];
  __shared__ float scl[64], shf[64];
  if(tid < 64){ scl[tid]=scale3[tid]; shf[tid]=shift3[tid]; }
  __syncthreads();
  for(int i=tid; i<4352; i+=256){
    int c = i/68, r = i%68, t = t0 - 2 + r;
    float val = 0.f;
    if(t >= 0 && t < T_) val = fmaxf(C1[((size_t)b*64+c)*T_ + t]*scl[c] + shf[c], 0.f);
    zT[r*72 + c] = (short)f2bits(val);
  }
  __syncthreads();
  int o0 = w*32;
  #pragma unroll
  for(int tt=0; tt<2; tt++){
    int twv = tt*32;
    f32x16 acc = {};
    #pragma unroll
    for(int kc=0; kc<12; kc++){
      bf16x8 af = *(const bf16x8*)&Wb2[((kc*128) + o0 + (lane&31))*16 + (lane>>5)*8];
      bf16x8 bfr = *(const bf16x8*)&zT[(twv + (lane&31) + 2*(kc>>2))*72 + (kc&3)*16 + (lane>>5)*8];
      acc = __builtin_amdgcn_mfma_f32_32x32x16_bf16(af, bfr, acc, 0, 0, 0);
    }
    int t = t0 + twv + (lane&31);
    #pragma unroll
    for(int r=0;r<16;r++){
      int o = o0 + (r&3) + 8*(r>>2) + 4*(lane>>5);
      C2[((size_t)b*128 + o)*T_ + t] = acc[r] + c2b[o];
    }
  }
}

// ---------------- per-channel stats over C (B, nch, T) ----------------
__global__ __launch_bounds__(256) void k_stats_ch(const float* __restrict__ C,
    float* __restrict__ sum, float* __restrict__ sq, int nch)
{
  int o = blockIdx.x, tid = threadIdx.x;
  float s=0.f, q=0.f;
  for(int idx = tid; idx < 64*128; idx += 256){
    int b = idx >> 7, t4 = idx & 127;
    float4 vv = *(const float4*)&C[((size_t)(b*nch+o))*T_ + t4*4];
    s += vv.x+vv.y+vv.z+vv.w;
    q += vv.x*vv.x + vv.y*vv.y + vv.z*vv.z + vv.w*vv.w;
  }
  for(int off=32; off; off>>=1){ s += __shfl_down(s, off); q += __shfl_down(q, off); }
  __shared__ float rs[4], rq[4];
  if((tid&63)==0){ rs[tid>>6]=s; rq[tid>>6]=q; }
  __syncthreads();
  if(tid==0){ sum[o] = rs[0]+rs[1]+rs[2]+rs[3]; sq[o] = rq[0]+rq[1]+rq[2]+rq[3]; }
}

// ---------------- head ----------------
__global__ __launch_bounds__(256) void k_head(
    const float* __restrict__ C2, const float* __restrict__ scale4, const float* __restrict__ shift4,
    const float* __restrict__ fcW, const float* __restrict__ fcb, float* __restrict__ out)
{
  int b = blockIdx.x, tid = threadIdx.x;
  __shared__ float mean[128];
  __shared__ float ms[256];
  int ch = tid >> 1, p = tid & 1;
  float scl = scale4[ch], shf = shift4[ch];
  const float* src = C2 + ((size_t)b*128 + ch)*T_ + p*256;
  float s = 0.f;
  for(int i=0;i<64;i++){
    float4 v4 = *(const float4*)&src[i*4];
    s += fmaxf(v4.x*scl + shf, 0.f) + fmaxf(v4.y*scl + shf, 0.f)
       + fmaxf(v4.z*scl + shf, 0.f) + fmaxf(v4.w*scl + shf, 0.f);
  }
  ms[tid] = s;
  __syncthreads();
  if(tid < 128) mean[tid] = (ms[2*tid] + ms[2*tid+1]) * (1.0f/512.0f);
  __syncthreads();
  if(tid < NC_){
    float acc = fcb[tid];
    for(int c=0;c<128;c++) acc += mean[c]*fcW[c*NC_ + tid];
    out[b*NC_ + tid] = acc;
  }
}

// ---------------- launch ----------------
extern "C" void kernel_launch(void* const* d_in, const int* in_sizes, int n_in,
                              void* d_out, int out_size, void* d_ws, size_t ws_size,
                              hipStream_t stream)
{
  const float* X   = (const float*)d_in[0];
  const int*   ei  = (const int*)  d_in[1];
  const float* W1  = (const float*)d_in[2];
  const float* s1W = (const float*)d_in[3];
  const float* s1b = (const float*)d_in[4];
  const float* g1  = (const float*)d_in[5];
  const float* b1  = (const float*)d_in[6];
  const float* W2  = (const float*)d_in[7];
  const float* s2W = (const float*)d_in[8];
  const float* s2b = (const float*)d_in[9];
  const float* g2  = (const float*)d_in[10];
  const float* b2  = (const float*)d_in[11];
  const float* c1W = (const float*)d_in[12];
  const float* c1b = (const float*)d_in[13];
  const float* tg1 = (const float*)d_in[14];
  const float* tb1 = (const float*)d_in[15];
  const float* c2W = (const float*)d_in[16];
  const float* c2b = (const float*)d_in[17];
  const float* tg2 = (const float*)d_in[18];
  const float* tb2 = (const float*)d_in[19];
  const float* fcW = (const float*)d_in[20];
  const float* fcb = (const float*)d_in[21];

  char* ws = (char*)d_ws;
  bf16*  H     = (bf16*) (ws);                       // 104,857,600 B
  float* C1    = (float*)(ws + 104857600);           // 8 MB
  // 16.7 MB region triple-used (dependency-ordered): BN partials -> conv1 P -> conv2 C2
  float* part  = (float*)(ws + 113246208);
  float* P     = part;
  float* C2    = part;
  bf16*  Wb    = (bf16*) (ws + 130023424);
  bf16*  Wb2   = (bf16*) (ws + 131252224);           // 49,152 B
  bf16*  WbB   = (bf16*) (ws + 131350528);
  float* stats = (float*)(ws + 131366912);
  float* sum3 = stats + 131072;   float* sq3 = sum3 + 64;
  float* sum4 = sq3 + 64;         float* sq4 = sum4 + 128;
  float* scale1 = stats + 131456; float* shift1 = scale1 + 32768;
  float* scale2 = shift1 + 32768; float* shift2 = scale2 + 32768;
  float* scale3 = shift2 + 32768; float* shift3 = scale3 + 64;
  float* scale4 = shift3 + 64;    float* shift4 = scale4 + 128;
  int* csr_off = (int*)(shift4 + 128);
  int* csr_lst = csr_off + 32;

  hipMemsetAsync(sum3, 0, 384*sizeof(float), stream);
  k_csr<<<1, 64, 0, stream>>>(ei, csr_off, csr_lst);
  k_wt<<<256, 256, 0, stream>>>(c1W, c2W, s2W, W2, Wb, Wb2, WbB);

  k_gcn1<<<dim3(T_/16, B_), 512, 0, stream>>>(X, s1W, W1, s1b, csr_off, csr_lst, H, part);
  k_bnfin_th<<<128, 256, 0, stream>>>(part, g1, b1, scale1, shift1);
  k_gcn2<<<dim3(T_/16, B_), 512, 0, stream>>>(H, H, scale1, shift1, WbB, s2b, csr_off, csr_lst, part);
  k_bnfin_th<<<128, 256, 0, stream>>>(part, g2, b2, scale2, shift2);
  k_conv1<<<dim3(8, B_, 2), 256, 0, stream>>>(H, scale2, shift2, Wb, P);
  k_red1<<<dim3(64, B_), 128, 0, stream>>>(P, c1b, C1, sum3, sq3);
  k_bnfin_ch<<<1, 64, 0, stream>>>(sum3, sq3, tg1, tb1, scale3, shift3, 64, 1.0f/32768.0f);
  k_conv2<<<dim3(8, B_), 256, 0, stream>>>(C1, scale3, shift3, Wb2, c2b, C2);
  k_stats_ch<<<128, 256, 0, stream>>>(C2, sum4, sq4, 128);
  k_bnfin_ch<<<1, 128, 0, stream>>>(sum4, sq4, tg2, tb2, scale4, shift4, 128, 1.0f/32768.0f);
  k_head<<<B_, 256, 0, stream>>>(C2, scale4, shift4, fcW, fcb, (float*)d_out);
}